// Round 1
// 14660.486 us; speedup vs baseline: 1.2815x; 1.2815x over previous
//
#include <hip/hip_runtime.h>
#include <hip/hip_bf16.h>
#include <math.h>

#define BATCH   16
#define SEQ     768
#define DMODEL  512
#define DSTATE  128
#define DINNER  1024
#define NHEADS  16
#define HEADDIM 64
#define CONVDIM 1280            // DINNER + 2*DSTATE
#define DINPROJ 2320            // 2*DINNER + 2*DSTATE + NHEADS
#define DINPROJP 2432           // padded to multiple of 128 for GEMM tiles
#define NLAYER  28
#define VOCABSZ 256
#define NROWS   (BATCH*SEQ)     // 12288
#define EPSV    1e-5f
#define NCH     8               // chunks per sequence
#define CH      96              // SEQ / NCH
#define STATESZ (HEADDIM*DSTATE) // 8192 floats per (b,h,chunk)

typedef __hip_bfloat16 bf16_t;
typedef __attribute__((ext_vector_type(8))) __bf16 bf16x8;
typedef __attribute__((ext_vector_type(4))) float floatx4;

__device__ __forceinline__ float siluf(float v) { return v / (1.f + expf(-v)); }

// ---------------- embed + residual zero + embedding bf16 cvt, one dispatch ----------------
__global__ __launch_bounds__(256) void embed_kernel(const int* __restrict__ tok,
    const float* __restrict__ emb, float* __restrict__ hid, float* __restrict__ res,
    bf16_t* __restrict__ w_emb_bf) {
  int i = blockIdx.x * 256 + threadIdx.x;
  const int total = NROWS * DMODEL;
  if (i < total) {
    int r = i >> 9;               // / DMODEL
    int d = i & (DMODEL - 1);
    hid[i] = emb[(size_t)tok[r] * DMODEL + d];
    res[i] = 0.f;
  } else {
    int j = i - total;
    if (j < VOCABSZ * DMODEL) w_emb_bf[j] = __float2bfloat16(emb[j]);
  }
}

// ---------------- per-layer weight conversion, one dispatch ----------------
__global__ __launch_bounds__(256) void cvt_weights_kernel(const float* __restrict__ ipw,
    const float* __restrict__ opw, bf16_t* __restrict__ win, bf16_t* __restrict__ wout) {
  int i = blockIdx.x * 256 + threadIdx.x;
  const int n1 = DINPROJP * DMODEL;
  if (i < n1) {
    int row = i >> 9, col = i & (DMODEL - 1);
    float v = (row < DINPROJ) ? ipw[(size_t)row * DMODEL + col] : 0.f;
    win[i] = __float2bfloat16(v);
  } else {
    int j = i - n1;
    if (j < DMODEL * DINNER) wout[j] = __float2bfloat16(opw[j]);
  }
}

// ---------------- residual add + RMSNorm (512 cols), bf16 out ----------------
__global__ __launch_bounds__(128) void prenorm_kernel(const float* __restrict__ h,
    float* __restrict__ res, const float* __restrict__ w, bf16_t* __restrict__ xn) {
  int row = blockIdx.x;
  int tid = threadIdx.x;        // 128 threads, one float4 each (512 cols)
  const float4* h4 = (const float4*)(h + (size_t)row * DMODEL);
  float4* r4 = (float4*)(res + (size_t)row * DMODEL);
  float4 v = r4[tid];
  float4 a = h4[tid];
  v.x += a.x; v.y += a.y; v.z += a.z; v.w += a.w;
  r4[tid] = v;
  float ss = v.x * v.x + v.y * v.y + v.z * v.z + v.w * v.w;
  #pragma unroll
  for (int o = 32; o > 0; o >>= 1) ss += __shfl_down(ss, o);
  __shared__ float wred[2];
  if ((tid & 63) == 0) wred[tid >> 6] = ss;
  __syncthreads();
  float tot = wred[0] + wred[1];
  float scale = rsqrtf(tot / (float)DMODEL + EPSV);
  const float4* w4 = (const float4*)w;
  float4 wv = w4[tid];
  union { bf16_t b[4]; uint2 u; } pk;
  pk.b[0] = __float2bfloat16(v.x * scale * wv.x);
  pk.b[1] = __float2bfloat16(v.y * scale * wv.y);
  pk.b[2] = __float2bfloat16(v.z * scale * wv.z);
  pk.b[3] = __float2bfloat16(v.w * scale * wv.w);
  ((uint2*)(xn + (size_t)row * DMODEL))[tid] = pk.u;
}

// ---------------- bf16 MFMA GEMM: C[M,N] = A[M,K] * B[N,K]^T ----------------
// 128xBN tile, 4 waves; BN=128 -> wave 64x64 (4x4 frags), BN=64 -> wave 64x32 (4x2)
template<int BN>
__global__ __launch_bounds__(256) void gemm_bf16_bt(const bf16_t* __restrict__ A,
    const bf16_t* __restrict__ B, float* __restrict__ C, int M, int N, int K) {
  constexpr int JF = BN / 32;           // n-frags per wave
  __shared__ bf16_t As[128 * 32];
  __shared__ bf16_t Bs[BN * 32];
  int tid = threadIdx.x;
  int m0 = blockIdx.y * 128;
  int n0 = blockIdx.x * BN;
  int w = tid >> 6, lane = tid & 63;
  int wm = (w >> 1) * 64, wn = (w & 1) * (BN / 2);
  int l16 = lane & 15, lq = lane >> 4;
  floatx4 acc[4][JF];
  #pragma unroll
  for (int i = 0; i < 4; ++i)
    #pragma unroll
    for (int j = 0; j < JF; ++j)
      acc[i][j] = (floatx4){0.f, 0.f, 0.f, 0.f};
  int arow0 = tid >> 2, ak0 = (tid & 3) * 8;   // rows 0..63, k-seg 0..3
  const bf16_t* Abase = A + (size_t)m0 * K;
  const bf16_t* Bbase = B + (size_t)n0 * K;
  for (int k0 = 0; k0 < K; k0 += 32) {
    uint4 va0 = *(const uint4*)(Abase + (size_t)arow0 * K + k0 + ak0);
    uint4 va1 = *(const uint4*)(Abase + (size_t)(arow0 + 64) * K + k0 + ak0);
    uint4 vb0 = *(const uint4*)(Bbase + (size_t)arow0 * K + k0 + ak0);
    uint4 vb1;
    if (BN == 128) vb1 = *(const uint4*)(Bbase + (size_t)(arow0 + 64) * K + k0 + ak0);
    __syncthreads();
    *(uint4*)(As + tid * 8) = va0;
    *(uint4*)(As + (tid + 256) * 8) = va1;
    *(uint4*)(Bs + tid * 8) = vb0;
    if (BN == 128) *(uint4*)(Bs + (tid + 256) * 8) = vb1;
    __syncthreads();
    bf16x8 af[4], bfr[JF];
    #pragma unroll
    for (int i = 0; i < 4; ++i)
      af[i] = *(const bf16x8*)(As + (wm + i * 16 + l16) * 32 + lq * 8);
    #pragma unroll
    for (int j = 0; j < JF; ++j)
      bfr[j] = *(const bf16x8*)(Bs + (wn + j * 16 + l16) * 32 + lq * 8);
    #pragma unroll
    for (int i = 0; i < 4; ++i)
      #pragma unroll
      for (int j = 0; j < JF; ++j)
        acc[i][j] = __builtin_amdgcn_mfma_f32_16x16x32_bf16(af[i], bfr[j], acc[i][j], 0, 0, 0);
  }
  #pragma unroll
  for (int i = 0; i < 4; ++i) {
    #pragma unroll
    for (int j = 0; j < JF; ++j) {
      int n = n0 + wn + j * 16 + l16;
      if (n < N) {
        int mb = m0 + wm + i * 16 + lq * 4;
        #pragma unroll
        for (int r = 0; r < 4; ++r)
          C[(size_t)(mb + r) * N + n] = acc[i][j][r];
      }
    }
  }
}

// ---------------- fused causal conv (width 4) + silu + dt/dA ----------------
__global__ __launch_bounds__(320) void convdt_kernel(const float* __restrict__ zx,
    const float* __restrict__ cw, const float* __restrict__ cb,
    const float* __restrict__ dt_bias, const float* __restrict__ A_log,
    float* __restrict__ out, float* __restrict__ dt, float* __restrict__ dA) {
  int bl = blockIdx.x;                         // 0..NROWS-1
  int t = bl % SEQ;
  int tid = threadIdx.x;                       // 0..319
  int c = tid * 4;
  const float* base = zx + (size_t)bl * DINPROJ + DINNER + c;
  float4 acc = *(const float4*)(cb + c);
  #pragma unroll
  for (int k = 0; k < 4; ++k) {
    int tt = t + k - 3;
    if (tt >= 0) {
      float4 v = *(const float4*)(base + (ptrdiff_t)(k - 3) * DINPROJ);
      acc.x += v.x * cw[(c + 0) * 4 + k];
      acc.y += v.y * cw[(c + 1) * 4 + k];
      acc.z += v.z * cw[(c + 2) * 4 + k];
      acc.w += v.w * cw[(c + 3) * 4 + k];
    }
  }
  float4 o;
  o.x = siluf(acc.x); o.y = siluf(acc.y); o.z = siluf(acc.z); o.w = siluf(acc.w);
  *(float4*)(out + (size_t)bl * CONVDIM + c) = o;
  if (tid < NHEADS) {
    int h = tid;
    float v = zx[(size_t)bl * DINPROJ + (DINNER + CONVDIM) + h] + dt_bias[h];
    float sp = fmaxf(v, 0.f) + log1pf(expf(-fabsf(v)));
    float Ah = -expf(A_log[h]);
    dt[bl * NHEADS + h] = sp;
    dA[bl * NHEADS + h] = expf(sp * Ah);
  }
}

// ---------------- chunked SSD scan, pass 1: LDS-staged local scan ----------------
__global__ __launch_bounds__(256) void scan_local_kernel(const float* __restrict__ conv,
    const float* __restrict__ dtb, const float* __restrict__ dAb,
    const float* __restrict__ Dp, float* __restrict__ y,
    float* __restrict__ state, float* __restrict__ chunkprod) {
  int c = blockIdx.x;
  int bh = blockIdx.y;
  int b = bh >> 4, h = bh & 15;
  int tid = threadIdx.x;
  int s = tid >> 6;               // wave id: n-slice [32s, 32s+32)
  int p = tid & 63;               // lane = headdim index
  float hs[32];
  #pragma unroll
  for (int j = 0; j < 32; ++j) hs[j] = 0.f;
  float Dh = Dp[h];
  float prod = 1.f;
  __shared__ float BC[8][256];    // [tc][0..127]=B, [128..255]=C
  __shared__ float xs[8][64];
  __shared__ float dtA[16];       // [0..7]=dt, [8..15]=dA
  __shared__ float yred[8][4][64];
  const int tstart = c * CH;
  const size_t row0 = (size_t)(b * SEQ + tstart);

  // staging index precompute
  int i0 = tid, i1 = tid + 256;                 // BC float4 slots
  int bct0 = i0 >> 6, bco0 = (i0 & 63) * 4;
  int bct1 = i1 >> 6, bco1 = (i1 & 63) * 4;
  int xt = tid >> 4, xo = (tid & 15) * 4;       // xs float4 slots (tid<128)

  float4 r0, r1, rx = make_float4(0.f, 0.f, 0.f, 0.f);
  float rsc = 0.f;
  {
    // prologue: load group 0
    size_t rb = row0 * CONVDIM + DINNER;
    r0 = *(const float4*)(conv + rb + (size_t)bct0 * CONVDIM + bco0);
    r1 = *(const float4*)(conv + rb + (size_t)bct1 * CONVDIM + bco1);
    if (tid < 128) rx = *(const float4*)(conv + (row0 + xt) * CONVDIM + h * HEADDIM + xo);
    else if (tid < 136) rsc = dtb[(row0 + (tid - 128)) * NHEADS + h];
    else if (tid < 144) rsc = dAb[(row0 + (tid - 136)) * NHEADS + h];
  }

  for (int g = 0; g < CH / 8; ++g) {
    __syncthreads();              // previous iteration's LDS readers done
    *(float4*)&BC[bct0][bco0] = r0;
    *(float4*)&BC[bct1][bco1] = r1;
    if (tid < 128) *(float4*)&xs[xt][xo] = rx;
    else if (tid < 144) dtA[tid - 128] = rsc;
    __syncthreads();
    if (g + 1 < CH / 8) {
      size_t rb = (row0 + (g + 1) * 8) * CONVDIM + DINNER;
      r0 = *(const float4*)(conv + rb + (size_t)bct0 * CONVDIM + bco0);
      r1 = *(const float4*)(conv + rb + (size_t)bct1 * CONVDIM + bco1);
      if (tid < 128) rx = *(const float4*)(conv + (row0 + (g + 1) * 8 + xt) * CONVDIM + h * HEADDIM + xo);
      else if (tid < 136) rsc = dtb[(row0 + (g + 1) * 8 + (tid - 128)) * NHEADS + h];
      else if (tid < 144) rsc = dAb[(row0 + (g + 1) * 8 + (tid - 136)) * NHEADS + h];
    }
    #pragma unroll
    for (int tc = 0; tc < 8; ++tc) {
      float x = xs[tc][p];
      float dtv = dtA[tc];
      float dAv = dtA[8 + tc];
      float dtx = dtv * x;
      prod *= dAv;
      const float4* Bq = (const float4*)&BC[tc][s * 32];
      const float4* Cq = (const float4*)&BC[tc][128 + s * 32];
      float y0 = 0.f, y1 = 0.f, y2 = 0.f, y3 = 0.f;
      #pragma unroll
      for (int q = 0; q < 8; ++q) {
        float4 Bv = Bq[q];
        float4 Cv = Cq[q];
        hs[q * 4 + 0] = dAv * hs[q * 4 + 0] + dtx * Bv.x; y0 += hs[q * 4 + 0] * Cv.x;
        hs[q * 4 + 1] = dAv * hs[q * 4 + 1] + dtx * Bv.y; y1 += hs[q * 4 + 1] * Cv.y;
        hs[q * 4 + 2] = dAv * hs[q * 4 + 2] + dtx * Bv.z; y2 += hs[q * 4 + 2] * Cv.z;
        hs[q * 4 + 3] = dAv * hs[q * 4 + 3] + dtx * Bv.w; y3 += hs[q * 4 + 3] * Cv.w;
      }
      float yp = (y0 + y1) + (y2 + y3);
      if (s == 0) yp += Dh * x;
      yred[tc][s][p] = yp;
    }
    __syncthreads();
    for (int i = tid; i < 512; i += 256) {
      int tc = i >> 6, pp = i & 63;
      float v = yred[tc][0][pp] + yred[tc][1][pp] + yred[tc][2][pp] + yred[tc][3][pp];
      y[((size_t)(row0 + g * 8 + tc) * NHEADS + h) * HEADDIM + pp] = v;
    }
  }
  size_t sbase = ((size_t)bh * NCH + c) * STATESZ;
  #pragma unroll
  for (int j = 0; j < 32; ++j)
    state[sbase + (size_t)(s * 32 + j) * HEADDIM + p] = hs[j];
  if (tid == 0) chunkprod[bh * NCH + c] = prod;
}

// ---------------- inter-chunk state recurrence: H_in[c] = P[c-1]*H_in[c-1] + S[c-1] ----------------
// In-place: slot c-1 of state becomes H_in[c] (the combined incoming state for chunk c).
// Slot c is read (original S_c) only after slot c-1 was overwritten -> no hazard.
__global__ __launch_bounds__(256) void state_combine_kernel(float* __restrict__ state,
    const float* __restrict__ cprod) {
  int bh = blockIdx.x;
  int tid = threadIdx.x;
  float4* slab = (float4*)(state + (size_t)bh * NCH * STATESZ);
  float4 H[8];
  #pragma unroll
  for (int q = 0; q < 8; ++q) H[q] = make_float4(0.f, 0.f, 0.f, 0.f);
  for (int c = 1; c < NCH; ++c) {
    float P = cprod[bh * NCH + c - 1];
    float4* sp = slab + (size_t)(c - 1) * (STATESZ / 4);
    #pragma unroll
    for (int q = 0; q < 8; ++q) {
      float4 S = sp[q * 256 + tid];          // coalesced
      H[q].x = P * H[q].x + S.x; H[q].y = P * H[q].y + S.y;
      H[q].z = P * H[q].z + S.z; H[q].w = P * H[q].w + S.w;
    }
    #pragma unroll
    for (int q = 0; q < 8; ++q) sp[q * 256 + tid] = H[q];
  }
}

// ---------------- pass 2: y[t] += (cumA[t]*C_t) . H_in  (per chunk c>=1) ----------------
// C tile (96x128) staged in LDS with coalesced loads, rows pre-scaled by inclusive
// cumulative dA -> product loop is pure LDS-broadcast b128 + FMA with 24 indep accs.
// H_in (32KB) read from global, wave-coalesced 256B lines (L1-resident after wave 0).
__global__ __launch_bounds__(256) void ycorr_kernel(const float* __restrict__ conv,
    const float* __restrict__ dAb, const float* __restrict__ state,
    float* __restrict__ y) {
  int c = blockIdx.x + 1;
  int bh = blockIdx.y;
  int b = bh >> 4, h = bh & 15;
  int tid = threadIdx.x;
  __shared__ float Cs[CH][DSTATE];   // 48KB, cumA-prescaled C rows
  __shared__ float cA[CH];
  const int tstart = c * CH;

  // inclusive prefix product of dA within chunk
  if (tid < CH) cA[tid] = dAb[((size_t)(b * SEQ + tstart + tid)) * NHEADS + h];
  __syncthreads();
  for (int off = 1; off < CH; off <<= 1) {
    float tmp = 1.f;
    if (tid < CH && tid >= off) tmp = cA[tid - off];
    __syncthreads();
    if (tid < CH) cA[tid] *= tmp;
    __syncthreads();
  }

  // stage C (scaled): 3072 float4 slots, coalesced (wave covers 2 rows per step)
  const float* Cg = conv + (size_t)(b * SEQ + tstart) * CONVDIM + DINNER + DSTATE;
  #pragma unroll
  for (int j = 0; j < 12; ++j) {
    int idx = j * 256 + tid;
    int row = idx >> 5, col4 = (idx & 31) * 4;
    float4 v = *(const float4*)(Cg + (size_t)row * CONVDIM + col4);
    float a = cA[row];
    v.x *= a; v.y *= a; v.z *= a; v.w *= a;
    *(float4*)&Cs[row][col4] = v;
  }
  __syncthreads();

  // product: thread (s,p) owns rows t = s+4i, i=0..23
  int s = tid >> 6, p = tid & 63;
  const float* Hb = state + ((size_t)bh * NCH + (c - 1)) * STATESZ + p;
  float acc[CH / 4];
  #pragma unroll
  for (int i = 0; i < CH / 4; ++i) acc[i] = 0.f;
  for (int n = 0; n < DSTATE; n += 4) {
    float h0 = Hb[(size_t)(n + 0) * HEADDIM];
    float h1 = Hb[(size_t)(n + 1) * HEADDIM];
    float h2 = Hb[(size_t)(n + 2) * HEADDIM];
    float h3 = Hb[(size_t)(n + 3) * HEADDIM];
    #pragma unroll
    for (int i = 0; i < CH / 4; ++i) {
      int tt = s + i * 4;
      float4 Cv = *(const float4*)&Cs[tt][n];   // wave-broadcast, conflict-free
      acc[i] += Cv.x * h0 + Cv.y * h1 + Cv.z * h2 + Cv.w * h3;
    }
  }
  #pragma unroll
  for (int i = 0; i < CH / 4; ++i) {
    int tt = s + i * 4;
    size_t yi = ((size_t)(b * SEQ + tstart + tt) * NHEADS + h) * HEADDIM + p;
    y[yi] += acc[i];
  }
}

// ---------------- gated RMSNorm over 1024, bf16 out ----------------
__global__ __launch_bounds__(256) void gated_norm_kernel(const float* __restrict__ y,
    const float* __restrict__ zx, const float* __restrict__ gw, bf16_t* __restrict__ out) {
  int row = blockIdx.x;
  int tid = threadIdx.x;
  const float4* y4 = (const float4*)(y + (size_t)row * DINNER);
  const float4* z4 = (const float4*)(zx + (size_t)row * DINPROJ);
  float4 yv = y4[tid];
  float4 zv = z4[tid];
  float4 g;
  g.x = yv.x * siluf(zv.x); g.y = yv.y * siluf(zv.y);
  g.z = yv.z * siluf(zv.z); g.w = yv.w * siluf(zv.w);
  float ss = g.x * g.x + g.y * g.y + g.z * g.z + g.w * g.w;
  #pragma unroll
  for (int o = 32; o > 0; o >>= 1) ss += __shfl_down(ss, o);
  __shared__ float red[4];
  if ((tid & 63) == 0) red[tid >> 6] = ss;
  __syncthreads();
  float tot = red[0] + red[1] + red[2] + red[3];
  float scale = rsqrtf(tot / (float)DINNER + EPSV);
  const float4* g4 = (const float4*)gw;
  float4 wv = g4[tid];
  union { bf16_t b[4]; uint2 u; } pk;
  pk.b[0] = __float2bfloat16(g.x * scale * wv.x);
  pk.b[1] = __float2bfloat16(g.y * scale * wv.y);
  pk.b[2] = __float2bfloat16(g.z * scale * wv.z);
  pk.b[3] = __float2bfloat16(g.w * scale * wv.w);
  ((uint2*)(out + (size_t)row * DINNER))[tid] = pk.u;
}

// ---------------- per-row loss: lse - logit[target] ----------------
__global__ __launch_bounds__(256) void rowloss_kernel(const float* __restrict__ logits,
    const int* __restrict__ targets, float* __restrict__ rl) {
  int row = blockIdx.x * 4 + (threadIdx.x >> 6);
  int lane = threadIdx.x & 63;
  const float* lr = logits + (size_t)row * VOCABSZ;
  float4 v = ((const float4*)lr)[lane];
  float mx = fmaxf(fmaxf(v.x, v.y), fmaxf(v.z, v.w));
  #pragma unroll
  for (int o = 32; o > 0; o >>= 1) mx = fmaxf(mx, __shfl_down(mx, o));
  mx = __shfl(mx, 0);
  float e = expf(v.x - mx) + expf(v.y - mx) + expf(v.z - mx) + expf(v.w - mx);
  #pragma unroll
  for (int o = 32; o > 0; o >>= 1) e += __shfl_down(e, o);
  if (lane == 0) {
    float lse = logf(e) + mx;
    rl[row] = lse - lr[targets[row]];
  }
}

__global__ __launch_bounds__(256) void loss_reduce_kernel(const float* __restrict__ rl,
    float* __restrict__ out) {
  int tid = threadIdx.x;
  float ssum = 0.f;
  for (int i = tid; i < NROWS; i += 256) ssum += rl[i];
  #pragma unroll
  for (int o = 32; o > 0; o >>= 1) ssum += __shfl_down(ssum, o);
  __shared__ float red[4];
  if ((tid & 63) == 0) red[tid >> 6] = ssum;
  __syncthreads();
  if (tid == 0) out[0] = (red[0] + red[1] + red[2] + red[3]) / (float)NROWS;
}

extern "C" void kernel_launch(void* const* d_in, const int* in_sizes, int n_in,
                              void* d_out, int out_size, void* d_ws, size_t ws_size,
                              hipStream_t stream) {
  const int*   tokens       = (const int*)d_in[0];
  const int*   targets      = (const int*)d_in[1];
  const float* embedding    = (const float*)d_in[2];
  const float* in_proj_w    = (const float*)d_in[3];
  const float* conv_w       = (const float*)d_in[4];
  const float* conv_b       = (const float*)d_in[5];
  const float* dt_bias      = (const float*)d_in[6];
  const float* A_log        = (const float*)d_in[7];
  const float* Dp           = (const float*)d_in[8];
  const float* gnorm_w      = (const float*)d_in[9];
  const float* out_proj_w   = (const float*)d_in[10];
  const float* block_norm_w = (const float*)d_in[11];
  const float* norm_f_w     = (const float*)d_in[12];
  float* out = (float*)d_out;

  float* ws = (float*)d_ws;
  size_t off = 0;
  float* hidden   = ws + off; off += (size_t)NROWS * DMODEL;
  float* residual = ws + off; off += (size_t)NROWS * DMODEL;
  float* zx       = ws + off; off += (size_t)NROWS * DINPROJ;
  float* convo    = ws + off; off += (size_t)NROWS * CONVDIM;
  float* dtb      = ws + off; off += (size_t)NROWS * NHEADS;
  float* dAb      = ws + off; off += (size_t)NROWS * NHEADS;
  float* ybuf     = ws + off; off += (size_t)NROWS * DINNER;
  float* cprod    = ws + off; off += (size_t)BATCH * NHEADS * NCH;
  float* rowloss  = ws + off; off += NROWS;
  bf16_t* w_in_bf  = (bf16_t*)(ws + off); off += (size_t)DINPROJP * DMODEL / 2;
  bf16_t* w_out_bf = (bf16_t*)(ws + off); off += (size_t)DMODEL * DINNER / 2;
  bf16_t* w_emb_bf = (bf16_t*)(ws + off); off += (size_t)VOCABSZ * DMODEL / 2;
  // union region: state (16.78M floats) vs bf16 activations (disjoint live ranges)
  float*  state  = ws + off;
  bf16_t* xn_bf  = (bf16_t*)(ws + off);   // live prenorm -> gemm1
  bf16_t* yn_bf  = (bf16_t*)(ws + off);   // live gated_norm -> gemm2
  off += (size_t)BATCH * NHEADS * NCH * STATESZ;

  embed_kernel<<<(NROWS * DMODEL + VOCABSZ * DMODEL) / 256, 256, 0, stream>>>(
      tokens, embedding, hidden, residual, w_emb_bf);

  const int cvt_total = DINPROJP * DMODEL + DMODEL * DINNER;
  for (int l = 0; l < NLAYER; ++l) {
    const float* ipw = in_proj_w + (size_t)l * DINPROJ * DMODEL;
    const float* cw  = conv_w + (size_t)l * CONVDIM * 4;
    const float* cb  = conv_b + (size_t)l * CONVDIM;
    const float* dtbias_l = dt_bias + (size_t)l * NHEADS;
    const float* alog_l   = A_log + (size_t)l * NHEADS;
    const float* D_l      = Dp + (size_t)l * NHEADS;
    const float* gw  = gnorm_w + (size_t)l * DINNER;
    const float* opw = out_proj_w + (size_t)l * DMODEL * DINNER;
    const float* bnw = block_norm_w + (size_t)l * DMODEL;

    cvt_weights_kernel<<<(cvt_total + 255) / 256, 256, 0, stream>>>(ipw, opw, w_in_bf, w_out_bf);
    prenorm_kernel<<<NROWS, 128, 0, stream>>>(hidden, residual, bnw, xn_bf);
    dim3 g1(DINPROJP / 128, NROWS / 128);
    gemm_bf16_bt<128><<<g1, 256, 0, stream>>>(xn_bf, w_in_bf, zx, NROWS, DINPROJ, DMODEL);
    convdt_kernel<<<NROWS, 320, 0, stream>>>(zx, cw, cb, dtbias_l, alog_l, convo, dtb, dAb);
    scan_local_kernel<<<dim3(NCH, BATCH * NHEADS), 256, 0, stream>>>(
        convo, dtb, dAb, D_l, ybuf, state, cprod);
    state_combine_kernel<<<BATCH * NHEADS, 256, 0, stream>>>(state, cprod);
    ycorr_kernel<<<dim3(NCH - 1, BATCH * NHEADS), 256, 0, stream>>>(
        convo, dAb, state, ybuf);
    gated_norm_kernel<<<NROWS, 256, 0, stream>>>(ybuf, zx, gw, yn_bf);
    dim3 g2(DMODEL / 64, NROWS / 128);
    gemm_bf16_bt<64><<<g2, 256, 0, stream>>>(yn_bf, w_out_bf, hidden, NROWS, DMODEL, DINNER);
  }

  prenorm_kernel<<<NROWS, 128, 0, stream>>>(hidden, residual, norm_f_w, xn_bf);
  dim3 g3(VOCABSZ / 64, NROWS / 128);
  gemm_bf16_bt<64><<<g3, 256, 0, stream>>>(xn_bf, w_emb_bf, out, NROWS, VOCABSZ, DMODEL);
  rowloss_kernel<<<NROWS / 4, 256, 0, stream>>>(out, targets, rowloss);
  loss_reduce_kernel<<<1, 256, 0, stream>>>(rowloss, out + (size_t)(out_size - 1));
}

// Round 4
// 12267.216 us; speedup vs baseline: 1.5316x; 1.1951x over previous
//
#include <hip/hip_runtime.h>
#include <hip/hip_bf16.h>
#include <math.h>

#define BATCH   16
#define SEQ     768
#define DMODEL  512
#define DSTATE  128
#define DINNER  1024
#define NHEADS  16
#define HEADDIM 64
#define CONVDIM 1280            // DINNER + 2*DSTATE
#define DINPROJ 2320            // 2*DINNER + 2*DSTATE + NHEADS
#define DINPROJP 2432           // padded to multiple of 128 for GEMM tiles
#define NLAYER  28
#define VOCABSZ 256
#define NROWS   (BATCH*SEQ)     // 12288
#define EPSV    1e-5f
#define NCH     8               // chunks per sequence
#define CH      96              // SEQ / NCH
#define STATESZ (HEADDIM*DSTATE) // 8192 floats per (b,h,chunk)

typedef __hip_bfloat16 bf16_t;
typedef __attribute__((ext_vector_type(8))) __bf16 bf16x8;
typedef __attribute__((ext_vector_type(4))) float floatx4;

__device__ __forceinline__ float siluf(float v) { return v / (1.f + expf(-v)); }

// ---------------- embed + residual zero + embedding bf16 cvt, one dispatch ----------------
__global__ __launch_bounds__(256) void embed_kernel(const int* __restrict__ tok,
    const float* __restrict__ emb, float* __restrict__ hid, float* __restrict__ res,
    bf16_t* __restrict__ w_emb_bf) {
  int i = blockIdx.x * 256 + threadIdx.x;
  const int total = NROWS * DMODEL;
  if (i < total) {
    int r = i >> 9;               // / DMODEL
    int d = i & (DMODEL - 1);
    hid[i] = emb[(size_t)tok[r] * DMODEL + d];
    res[i] = 0.f;
  } else {
    int j = i - total;
    if (j < VOCABSZ * DMODEL) w_emb_bf[j] = __float2bfloat16(emb[j]);
  }
}

// ---------------- per-layer weight conversion, one dispatch ----------------
__global__ __launch_bounds__(256) void cvt_weights_kernel(const float* __restrict__ ipw,
    const float* __restrict__ opw, bf16_t* __restrict__ win, bf16_t* __restrict__ wout) {
  int i = blockIdx.x * 256 + threadIdx.x;
  const int n1 = DINPROJP * DMODEL;
  if (i < n1) {
    int row = i >> 9, col = i & (DMODEL - 1);
    float v = (row < DINPROJ) ? ipw[(size_t)row * DMODEL + col] : 0.f;
    win[i] = __float2bfloat16(v);
  } else {
    int j = i - n1;
    if (j < DMODEL * DINNER) wout[j] = __float2bfloat16(opw[j]);
  }
}

// ---------------- residual add + RMSNorm (512 cols), bf16 out ----------------
__global__ __launch_bounds__(128) void prenorm_kernel(const float* __restrict__ h,
    float* __restrict__ res, const float* __restrict__ w, bf16_t* __restrict__ xn) {
  int row = blockIdx.x;
  int tid = threadIdx.x;        // 128 threads, one float4 each (512 cols)
  const float4* h4 = (const float4*)(h + (size_t)row * DMODEL);
  float4* r4 = (float4*)(res + (size_t)row * DMODEL);
  float4 v = r4[tid];
  float4 a = h4[tid];
  v.x += a.x; v.y += a.y; v.z += a.z; v.w += a.w;
  r4[tid] = v;
  float ss = v.x * v.x + v.y * v.y + v.z * v.z + v.w * v.w;
  #pragma unroll
  for (int o = 32; o > 0; o >>= 1) ss += __shfl_down(ss, o);
  __shared__ float wred[2];
  if ((tid & 63) == 0) wred[tid >> 6] = ss;
  __syncthreads();
  float tot = wred[0] + wred[1];
  float scale = rsqrtf(tot / (float)DMODEL + EPSV);
  const float4* w4 = (const float4*)w;
  float4 wv = w4[tid];
  union { bf16_t b[4]; uint2 u; } pk;
  pk.b[0] = __float2bfloat16(v.x * scale * wv.x);
  pk.b[1] = __float2bfloat16(v.y * scale * wv.y);
  pk.b[2] = __float2bfloat16(v.z * scale * wv.z);
  pk.b[3] = __float2bfloat16(v.w * scale * wv.w);
  ((uint2*)(xn + (size_t)row * DMODEL))[tid] = pk.u;
}

// ---------------- bf16 MFMA GEMM: C[M,N] = A[M,K] * B[N,K]^T ----------------
// 128xBN tile, 4 waves; BN=128 -> wave 64x64 (4x4 frags), BN=64 -> wave 64x32 (4x2)
template<int BN>
__global__ __launch_bounds__(256) void gemm_bf16_bt(const bf16_t* __restrict__ A,
    const bf16_t* __restrict__ B, float* __restrict__ C, int M, int N, int K) {
  constexpr int JF = BN / 32;           // n-frags per wave
  __shared__ bf16_t As[128 * 32];
  __shared__ bf16_t Bs[BN * 32];
  int tid = threadIdx.x;
  int m0 = blockIdx.y * 128;
  int n0 = blockIdx.x * BN;
  int w = tid >> 6, lane = tid & 63;
  int wm = (w >> 1) * 64, wn = (w & 1) * (BN / 2);
  int l16 = lane & 15, lq = lane >> 4;
  floatx4 acc[4][JF];
  #pragma unroll
  for (int i = 0; i < 4; ++i)
    #pragma unroll
    for (int j = 0; j < JF; ++j)
      acc[i][j] = (floatx4){0.f, 0.f, 0.f, 0.f};
  int arow0 = tid >> 2, ak0 = (tid & 3) * 8;   // rows 0..63, k-seg 0..3
  const bf16_t* Abase = A + (size_t)m0 * K;
  const bf16_t* Bbase = B + (size_t)n0 * K;
  for (int k0 = 0; k0 < K; k0 += 32) {
    uint4 va0 = *(const uint4*)(Abase + (size_t)arow0 * K + k0 + ak0);
    uint4 va1 = *(const uint4*)(Abase + (size_t)(arow0 + 64) * K + k0 + ak0);
    uint4 vb0 = *(const uint4*)(Bbase + (size_t)arow0 * K + k0 + ak0);
    uint4 vb1;
    if (BN == 128) vb1 = *(const uint4*)(Bbase + (size_t)(arow0 + 64) * K + k0 + ak0);
    __syncthreads();
    *(uint4*)(As + tid * 8) = va0;
    *(uint4*)(As + (tid + 256) * 8) = va1;
    *(uint4*)(Bs + tid * 8) = vb0;
    if (BN == 128) *(uint4*)(Bs + (tid + 256) * 8) = vb1;
    __syncthreads();
    bf16x8 af[4], bfr[JF];
    #pragma unroll
    for (int i = 0; i < 4; ++i)
      af[i] = *(const bf16x8*)(As + (wm + i * 16 + l16) * 32 + lq * 8);
    #pragma unroll
    for (int j = 0; j < JF; ++j)
      bfr[j] = *(const bf16x8*)(Bs + (wn + j * 16 + l16) * 32 + lq * 8);
    #pragma unroll
    for (int i = 0; i < 4; ++i)
      #pragma unroll
      for (int j = 0; j < JF; ++j)
        acc[i][j] = __builtin_amdgcn_mfma_f32_16x16x32_bf16(af[i], bfr[j], acc[i][j], 0, 0, 0);
  }
  #pragma unroll
  for (int i = 0; i < 4; ++i) {
    #pragma unroll
    for (int j = 0; j < JF; ++j) {
      int n = n0 + wn + j * 16 + l16;
      if (n < N) {
        int mb = m0 + wm + i * 16 + lq * 4;
        #pragma unroll
        for (int r = 0; r < 4; ++r)
          C[(size_t)(mb + r) * N + n] = acc[i][j][r];
      }
    }
  }
}

// ---------------- fused causal conv (width 4) + silu + dt/dA ----------------
// 4 consecutive timesteps per block via 7-row register sliding window:
// 7 row-loads instead of 16 (per 4 outputs), blocks 12288 -> 3072.
__global__ __launch_bounds__(320) void convdt_kernel(const float* __restrict__ zx,
    const float* __restrict__ cw, const float* __restrict__ cb,
    const float* __restrict__ dt_bias, const float* __restrict__ A_log,
    float* __restrict__ out, float* __restrict__ dt, float* __restrict__ dA) {
  int bl0 = blockIdx.x * 4;                    // 4 consecutive rows, same sequence (SEQ%4==0)
  int t0 = bl0 % SEQ;
  int tid = threadIdx.x;                       // 0..319
  int c = tid * 4;
  const float* base = zx + (size_t)bl0 * DINPROJ + DINNER + c;
  float4 v[7];
  #pragma unroll
  for (int k = 0; k < 7; ++k) {
    int tt = t0 + k - 3;
    if (tt >= 0)
      v[k] = *(const float4*)(base + (ptrdiff_t)(k - 3) * DINPROJ);
    else
      v[k] = make_float4(0.f, 0.f, 0.f, 0.f);
  }
  float4 w0 = *(const float4*)(cw + (size_t)(c + 0) * 4);
  float4 w1 = *(const float4*)(cw + (size_t)(c + 1) * 4);
  float4 w2 = *(const float4*)(cw + (size_t)(c + 2) * 4);
  float4 w3 = *(const float4*)(cw + (size_t)(c + 3) * 4);
  float4 bias = *(const float4*)(cb + c);
  const float* w0f = (const float*)&w0;
  const float* w1f = (const float*)&w1;
  const float* w2f = (const float*)&w2;
  const float* w3f = (const float*)&w3;
  #pragma unroll
  for (int j = 0; j < 4; ++j) {
    float4 acc = bias;
    #pragma unroll
    for (int k = 0; k < 4; ++k) {
      float4 vv = v[j + k];
      acc.x += vv.x * w0f[k];
      acc.y += vv.y * w1f[k];
      acc.z += vv.z * w2f[k];
      acc.w += vv.w * w3f[k];
    }
    float4 o;
    o.x = siluf(acc.x); o.y = siluf(acc.y); o.z = siluf(acc.z); o.w = siluf(acc.w);
    *(float4*)(out + (size_t)(bl0 + j) * CONVDIM + c) = o;
  }
  if (tid < 64) {
    int j = tid >> 4, h = tid & 15;
    int bl = bl0 + j;
    float vv = zx[(size_t)bl * DINPROJ + (DINNER + CONVDIM) + h] + dt_bias[h];
    float sp = fmaxf(vv, 0.f) + log1pf(expf(-fabsf(vv)));
    float Ah = -expf(A_log[h]);
    dt[bl * NHEADS + h] = sp;
    dA[bl * NHEADS + h] = expf(sp * Ah);
  }
}

// ---------------- chunked SSD scan, pass 1: LDS-staged local scan ----------------
__global__ __launch_bounds__(256) void scan_local_kernel(const float* __restrict__ conv,
    const float* __restrict__ dtb, const float* __restrict__ dAb,
    const float* __restrict__ Dp, float* __restrict__ y,
    float* __restrict__ state, float* __restrict__ chunkprod) {
  int c = blockIdx.x;
  int bh = blockIdx.y;
  int b = bh >> 4, h = bh & 15;
  int tid = threadIdx.x;
  int s = tid >> 6;               // wave id: n-slice [32s, 32s+32)
  int p = tid & 63;               // lane = headdim index
  float hs[32];
  #pragma unroll
  for (int j = 0; j < 32; ++j) hs[j] = 0.f;
  float Dh = Dp[h];
  float prod = 1.f;
  __shared__ float BC[8][256];    // [tc][0..127]=B, [128..255]=C
  __shared__ float xs[8][64];
  __shared__ float dtA[16];       // [0..7]=dt, [8..15]=dA
  __shared__ float yred[8][4][64];
  const int tstart = c * CH;
  const size_t row0 = (size_t)(b * SEQ + tstart);

  // staging index precompute
  int i0 = tid, i1 = tid + 256;                 // BC float4 slots
  int bct0 = i0 >> 6, bco0 = (i0 & 63) * 4;
  int bct1 = i1 >> 6, bco1 = (i1 & 63) * 4;
  int xt = tid >> 4, xo = (tid & 15) * 4;       // xs float4 slots (tid<128)

  float4 r0, r1, rx = make_float4(0.f, 0.f, 0.f, 0.f);
  float rsc = 0.f;
  {
    // prologue: load group 0
    size_t rb = row0 * CONVDIM + DINNER;
    r0 = *(const float4*)(conv + rb + (size_t)bct0 * CONVDIM + bco0);
    r1 = *(const float4*)(conv + rb + (size_t)bct1 * CONVDIM + bco1);
    if (tid < 128) rx = *(const float4*)(conv + (row0 + xt) * CONVDIM + h * HEADDIM + xo);
    else if (tid < 136) rsc = dtb[(row0 + (tid - 128)) * NHEADS + h];
    else if (tid < 144) rsc = dAb[(row0 + (tid - 136)) * NHEADS + h];
  }

  for (int g = 0; g < CH / 8; ++g) {
    __syncthreads();              // previous iteration's LDS readers done
    *(float4*)&BC[bct0][bco0] = r0;
    *(float4*)&BC[bct1][bco1] = r1;
    if (tid < 128) *(float4*)&xs[xt][xo] = rx;
    else if (tid < 144) dtA[tid - 128] = rsc;
    __syncthreads();
    if (g + 1 < CH / 8) {
      size_t rb = (row0 + (g + 1) * 8) * CONVDIM + DINNER;
      r0 = *(const float4*)(conv + rb + (size_t)bct0 * CONVDIM + bco0);
      r1 = *(const float4*)(conv + rb + (size_t)bct1 * CONVDIM + bco1);
      if (tid < 128) rx = *(const float4*)(conv + (row0 + (g + 1) * 8 + xt) * CONVDIM + h * HEADDIM + xo);
      else if (tid < 136) rsc = dtb[(row0 + (g + 1) * 8 + (tid - 128)) * NHEADS + h];
      else if (tid < 144) rsc = dAb[(row0 + (g + 1) * 8 + (tid - 136)) * NHEADS + h];
    }
    #pragma unroll
    for (int tc = 0; tc < 8; ++tc) {
      float x = xs[tc][p];
      float dtv = dtA[tc];
      float dAv = dtA[8 + tc];
      float dtx = dtv * x;
      prod *= dAv;
      const float4* Bq = (const float4*)&BC[tc][s * 32];
      const float4* Cq = (const float4*)&BC[tc][128 + s * 32];
      float y0 = 0.f, y1 = 0.f, y2 = 0.f, y3 = 0.f;
      #pragma unroll
      for (int q = 0; q < 8; ++q) {
        float4 Bv = Bq[q];
        float4 Cv = Cq[q];
        hs[q * 4 + 0] = dAv * hs[q * 4 + 0] + dtx * Bv.x; y0 += hs[q * 4 + 0] * Cv.x;
        hs[q * 4 + 1] = dAv * hs[q * 4 + 1] + dtx * Bv.y; y1 += hs[q * 4 + 1] * Cv.y;
        hs[q * 4 + 2] = dAv * hs[q * 4 + 2] + dtx * Bv.z; y2 += hs[q * 4 + 2] * Cv.z;
        hs[q * 4 + 3] = dAv * hs[q * 4 + 3] + dtx * Bv.w; y3 += hs[q * 4 + 3] * Cv.w;
      }
      float yp = (y0 + y1) + (y2 + y3);
      if (s == 0) yp += Dh * x;
      yred[tc][s][p] = yp;
    }
    __syncthreads();
    for (int i = tid; i < 512; i += 256) {
      int tc = i >> 6, pp = i & 63;
      float v = yred[tc][0][pp] + yred[tc][1][pp] + yred[tc][2][pp] + yred[tc][3][pp];
      y[((size_t)(row0 + g * 8 + tc) * NHEADS + h) * HEADDIM + pp] = v;
    }
  }
  size_t sbase = ((size_t)bh * NCH + c) * STATESZ;
  #pragma unroll
  for (int j = 0; j < 32; ++j)
    state[sbase + (size_t)(s * 32 + j) * HEADDIM + p] = hs[j];
  if (tid == 0) chunkprod[bh * NCH + c] = prod;
}

// ---------------- inter-chunk state recurrence: H_in[c] = P[c-1]*H_in[c-1] + S[c-1] ----------------
// Elementwise over the 8192-float state -> parallelize: 8 slice-blocks per bh
// (2048 blocks, 8 waves/SIMD) instead of 256 blocks (1 wave/SIMD, latency-exposed).
// In-place: slot c-1 becomes H_in[c]; slot c is read only after c-1 written -> no hazard.
__global__ __launch_bounds__(256) void state_combine_kernel(float* __restrict__ state,
    const float* __restrict__ cprod) {
  int bh = blockIdx.y;
  int sl = blockIdx.x;            // slice 0..7 (1024 floats each)
  int tid = threadIdx.x;
  float4* slab = (float4*)(state + (size_t)bh * NCH * STATESZ) + sl * 256 + tid;
  const float* pc = cprod + bh * NCH;
  float4 H = make_float4(0.f, 0.f, 0.f, 0.f);
  for (int c = 1; c < NCH; ++c) {
    float P = pc[c - 1];
    float4* sp = slab + (size_t)(c - 1) * (STATESZ / 4);
    float4 S = *sp;
    H.x = P * H.x + S.x; H.y = P * H.y + S.y;
    H.z = P * H.z + S.z; H.w = P * H.w + S.w;
    *sp = H;
  }
}

// ---------------- pass 2: y[t] += (cumA[t]*C_t) . H_in  (per chunk c>=1) ----------------
__global__ __launch_bounds__(256) void ycorr_kernel(const float* __restrict__ conv,
    const float* __restrict__ dAb, const float* __restrict__ state,
    float* __restrict__ y) {
  int c = blockIdx.x + 1;
  int bh = blockIdx.y;
  int b = bh >> 4, h = bh & 15;
  int tid = threadIdx.x;
  __shared__ float Cs[CH][DSTATE];   // 48KB, cumA-prescaled C rows
  __shared__ float cA[CH];
  const int tstart = c * CH;

  // inclusive prefix product of dA within chunk
  if (tid < CH) cA[tid] = dAb[((size_t)(b * SEQ + tstart + tid)) * NHEADS + h];
  __syncthreads();
  for (int off = 1; off < CH; off <<= 1) {
    float tmp = 1.f;
    if (tid < CH && tid >= off) tmp = cA[tid - off];
    __syncthreads();
    if (tid < CH) cA[tid] *= tmp;
    __syncthreads();
  }

  // stage C (scaled): 3072 float4 slots, coalesced (wave covers 2 rows per step)
  const float* Cg = conv + (size_t)(b * SEQ + tstart) * CONVDIM + DINNER + DSTATE;
  #pragma unroll
  for (int j = 0; j < 12; ++j) {
    int idx = j * 256 + tid;
    int row = idx >> 5, col4 = (idx & 31) * 4;
    float4 v = *(const float4*)(Cg + (size_t)row * CONVDIM + col4);
    float a = cA[row];
    v.x *= a; v.y *= a; v.z *= a; v.w *= a;
    *(float4*)&Cs[row][col4] = v;
  }
  __syncthreads();

  // product: thread (s,p) owns rows t = s+4i, i=0..23
  int s = tid >> 6, p = tid & 63;
  const float* Hb = state + ((size_t)bh * NCH + (c - 1)) * STATESZ + p;
  float acc[CH / 4];
  #pragma unroll
  for (int i = 0; i < CH / 4; ++i) acc[i] = 0.f;
  for (int n = 0; n < DSTATE; n += 4) {
    float h0 = Hb[(size_t)(n + 0) * HEADDIM];
    float h1 = Hb[(size_t)(n + 1) * HEADDIM];
    float h2 = Hb[(size_t)(n + 2) * HEADDIM];
    float h3 = Hb[(size_t)(n + 3) * HEADDIM];
    #pragma unroll
    for (int i = 0; i < CH / 4; ++i) {
      int tt = s + i * 4;
      float4 Cv = *(const float4*)&Cs[tt][n];   // wave-broadcast, conflict-free
      acc[i] += Cv.x * h0 + Cv.y * h1 + Cv.z * h2 + Cv.w * h3;
    }
  }
  #pragma unroll
  for (int i = 0; i < CH / 4; ++i) {
    int tt = s + i * 4;
    size_t yi = ((size_t)(b * SEQ + tstart + tt) * NHEADS + h) * HEADDIM + p;
    y[yi] += acc[i];
  }
}

// ---------------- gated RMSNorm over 1024, bf16 out ----------------
__global__ __launch_bounds__(256) void gated_norm_kernel(const float* __restrict__ y,
    const float* __restrict__ zx, const float* __restrict__ gw, bf16_t* __restrict__ out) {
  int row = blockIdx.x;
  int tid = threadIdx.x;
  const float4* y4 = (const float4*)(y + (size_t)row * DINNER);
  const float4* z4 = (const float4*)(zx + (size_t)row * DINPROJ);
  float4 yv = y4[tid];
  float4 zv = z4[tid];
  float4 g;
  g.x = yv.x * siluf(zv.x); g.y = yv.y * siluf(zv.y);
  g.z = yv.z * siluf(zv.z); g.w = yv.w * siluf(zv.w);
  float ss = g.x * g.x + g.y * g.y + g.z * g.z + g.w * g.w;
  #pragma unroll
  for (int o = 32; o > 0; o >>= 1) ss += __shfl_down(ss, o);
  __shared__ float red[4];
  if ((tid & 63) == 0) red[tid >> 6] = ss;
  __syncthreads();
  float tot = red[0] + red[1] + red[2] + red[3];
  float scale = rsqrtf(tot / (float)DINNER + EPSV);
  const float4* g4 = (const float4*)gw;
  float4 wv = g4[tid];
  union { bf16_t b[4]; uint2 u; } pk;
  pk.b[0] = __float2bfloat16(g.x * scale * wv.x);
  pk.b[1] = __float2bfloat16(g.y * scale * wv.y);
  pk.b[2] = __float2bfloat16(g.z * scale * wv.z);
  pk.b[3] = __float2bfloat16(g.w * scale * wv.w);
  ((uint2*)(out + (size_t)row * DINNER))[tid] = pk.u;
}

// ---------------- per-row loss: lse - logit[target] ----------------
__global__ __launch_bounds__(256) void rowloss_kernel(const float* __restrict__ logits,
    const int* __restrict__ targets, float* __restrict__ rl) {
  int row = blockIdx.x * 4 + (threadIdx.x >> 6);
  int lane = threadIdx.x & 63;
  const float* lr = logits + (size_t)row * VOCABSZ;
  float4 v = ((const float4*)lr)[lane];
  float mx = fmaxf(fmaxf(v.x, v.y), fmaxf(v.z, v.w));
  #pragma unroll
  for (int o = 32; o > 0; o >>= 1) mx = fmaxf(mx, __shfl_down(mx, o));
  mx = __shfl(mx, 0);
  float e = expf(v.x - mx) + expf(v.y - mx) + expf(v.z - mx) + expf(v.w - mx);
  #pragma unroll
  for (int o = 32; o > 0; o >>= 1) e += __shfl_down(e, o);
  if (lane == 0) {
    float lse = logf(e) + mx;
    rl[row] = lse - lr[targets[row]];
  }
}

__global__ __launch_bounds__(256) void loss_reduce_kernel(const float* __restrict__ rl,
    float* __restrict__ out) {
  int tid = threadIdx.x;
  float ssum = 0.f;
  for (int i = tid; i < NROWS; i += 256) ssum += rl[i];
  #pragma unroll
  for (int o = 32; o > 0; o >>= 1) ssum += __shfl_down(ssum, o);
  __shared__ float red[4];
  if ((tid & 63) == 0) red[tid >> 6] = ssum;
  __syncthreads();
  if (tid == 0) out[0] = (red[0] + red[1] + red[2] + red[3]) / (float)NROWS;
}

extern "C" void kernel_launch(void* const* d_in, const int* in_sizes, int n_in,
                              void* d_out, int out_size, void* d_ws, size_t ws_size,
                              hipStream_t stream) {
  const int*   tokens       = (const int*)d_in[0];
  const int*   targets      = (const int*)d_in[1];
  const float* embedding    = (const float*)d_in[2];
  const float* in_proj_w    = (const float*)d_in[3];
  const float* conv_w       = (const float*)d_in[4];
  const float* conv_b       = (const float*)d_in[5];
  const float* dt_bias      = (const float*)d_in[6];
  const float* A_log        = (const float*)d_in[7];
  const float* Dp           = (const float*)d_in[8];
  const float* gnorm_w      = (const float*)d_in[9];
  const float* out_proj_w   = (const float*)d_in[10];
  const float* block_norm_w = (const float*)d_in[11];
  const float* norm_f_w     = (const float*)d_in[12];
  float* out = (float*)d_out;

  float* ws = (float*)d_ws;
  size_t off = 0;
  float* hidden   = ws + off; off += (size_t)NROWS * DMODEL;
  float* residual = ws + off; off += (size_t)NROWS * DMODEL;
  float* zx       = ws + off; off += (size_t)NROWS * DINPROJ;
  float* convo    = ws + off; off += (size_t)NROWS * CONVDIM;
  float* dtb      = ws + off; off += (size_t)NROWS * NHEADS;
  float* dAb      = ws + off; off += (size_t)NROWS * NHEADS;
  float* ybuf     = ws + off; off += (size_t)NROWS * DINNER;
  float* cprod    = ws + off; off += (size_t)BATCH * NHEADS * NCH;
  float* rowloss  = ws + off; off += NROWS;
  bf16_t* w_in_bf  = (bf16_t*)(ws + off); off += (size_t)DINPROJP * DMODEL / 2;
  bf16_t* w_out_bf = (bf16_t*)(ws + off); off += (size_t)DMODEL * DINNER / 2;
  bf16_t* w_emb_bf = (bf16_t*)(ws + off); off += (size_t)VOCABSZ * DMODEL / 2;
  // union region: state (16.78M floats) vs bf16 activations (disjoint live ranges)
  float*  state  = ws + off;
  bf16_t* xn_bf  = (bf16_t*)(ws + off);   // live prenorm -> gemm1
  bf16_t* yn_bf  = (bf16_t*)(ws + off);   // live gated_norm -> gemm2
  off += (size_t)BATCH * NHEADS * NCH * STATESZ;

  embed_kernel<<<(NROWS * DMODEL + VOCABSZ * DMODEL) / 256, 256, 0, stream>>>(
      tokens, embedding, hidden, residual, w_emb_bf);

  const int cvt_total = DINPROJP * DMODEL + DMODEL * DINNER;
  for (int l = 0; l < NLAYER; ++l) {
    const float* ipw = in_proj_w + (size_t)l * DINPROJ * DMODEL;
    const float* cw  = conv_w + (size_t)l * CONVDIM * 4;
    const float* cb  = conv_b + (size_t)l * CONVDIM;
    const float* dtbias_l = dt_bias + (size_t)l * NHEADS;
    const float* alog_l   = A_log + (size_t)l * NHEADS;
    const float* D_l      = Dp + (size_t)l * NHEADS;
    const float* gw  = gnorm_w + (size_t)l * DINNER;
    const float* opw = out_proj_w + (size_t)l * DMODEL * DINNER;
    const float* bnw = block_norm_w + (size_t)l * DMODEL;

    cvt_weights_kernel<<<(cvt_total + 255) / 256, 256, 0, stream>>>(ipw, opw, w_in_bf, w_out_bf);
    prenorm_kernel<<<NROWS, 128, 0, stream>>>(hidden, residual, bnw, xn_bf);
    dim3 g1(DINPROJP / 128, NROWS / 128);
    gemm_bf16_bt<128><<<g1, 256, 0, stream>>>(xn_bf, w_in_bf, zx, NROWS, DINPROJ, DMODEL);
    convdt_kernel<<<NROWS / 4, 320, 0, stream>>>(zx, cw, cb, dtbias_l, alog_l, convo, dtb, dAb);
    scan_local_kernel<<<dim3(NCH, BATCH * NHEADS), 256, 0, stream>>>(
        convo, dtb, dAb, D_l, ybuf, state, cprod);
    state_combine_kernel<<<dim3(NCH, BATCH * NHEADS), 256, 0, stream>>>(state, cprod);
    ycorr_kernel<<<dim3(NCH - 1, BATCH * NHEADS), 256, 0, stream>>>(
        convo, dAb, state, ybuf);
    gated_norm_kernel<<<NROWS, 256, 0, stream>>>(ybuf, zx, gw, yn_bf);
    dim3 g2(DMODEL / 64, NROWS / 128);
    gemm_bf16_bt<64><<<g2, 256, 0, stream>>>(yn_bf, w_out_bf, hidden, NROWS, DMODEL, DINNER);
  }

  prenorm_kernel<<<NROWS, 128, 0, stream>>>(hidden, residual, norm_f_w, xn_bf);
  dim3 g3(VOCABSZ / 64, NROWS / 128);
  gemm_bf16_bt<64><<<g3, 256, 0, stream>>>(xn_bf, w_emb_bf, out, NROWS, VOCABSZ, DMODEL);
  rowloss_kernel<<<NROWS / 4, 256, 0, stream>>>(out, targets, rowloss);
  loss_reduce_kernel<<<1, 256, 0, stream>>>(rowloss, out + (size_t)(out_size - 1));
}

// Round 5
// 11884.866 us; speedup vs baseline: 1.5808x; 1.0322x over previous
//
#include <hip/hip_runtime.h>
#include <hip/hip_bf16.h>
#include <math.h>

#define BATCH   16
#define SEQ     768
#define DMODEL  512
#define DSTATE  128
#define DINNER  1024
#define NHEADS  16
#define HEADDIM 64
#define CONVDIM 1280            // DINNER + 2*DSTATE
#define DINPROJ 2320            // 2*DINNER + 2*DSTATE + NHEADS
#define DINPROJP 2432           // padded to multiple of 128 for GEMM tiles
#define NLAYER  28
#define VOCABSZ 256
#define NROWS   (BATCH*SEQ)     // 12288
#define EPSV    1e-5f
#define NCH     8               // chunks per sequence
#define CH      96              // SEQ / NCH
#define STATESZ (HEADDIM*DSTATE) // 8192 floats per (b,h,chunk)

typedef __hip_bfloat16 bf16_t;
typedef __attribute__((ext_vector_type(8))) __bf16 bf16x8;
typedef __attribute__((ext_vector_type(4))) float floatx4;

__device__ __forceinline__ float siluf(float v) { return v / (1.f + expf(-v)); }

// async global->LDS, 16B per lane; LDS dest = wave-uniform base + lane*16
__device__ __forceinline__ void gload_lds16(const bf16_t* g, bf16_t* l) {
  __builtin_amdgcn_global_load_lds(
      (const __attribute__((address_space(1))) unsigned int*)g,
      (__attribute__((address_space(3))) unsigned int*)l, 16, 0, 0);
}

// ---------------- embed + residual zero + embedding bf16 cvt, one dispatch ----------------
__global__ __launch_bounds__(256) void embed_kernel(const int* __restrict__ tok,
    const float* __restrict__ emb, float* __restrict__ hid, float* __restrict__ res,
    bf16_t* __restrict__ w_emb_bf) {
  int i = blockIdx.x * 256 + threadIdx.x;
  const int total = NROWS * DMODEL;
  if (i < total) {
    int r = i >> 9;               // / DMODEL
    int d = i & (DMODEL - 1);
    hid[i] = emb[(size_t)tok[r] * DMODEL + d];
    res[i] = 0.f;
  } else {
    int j = i - total;
    if (j < VOCABSZ * DMODEL) w_emb_bf[j] = __float2bfloat16(emb[j]);
  }
}

// ---------------- per-layer weight conversion, one dispatch ----------------
__global__ __launch_bounds__(256) void cvt_weights_kernel(const float* __restrict__ ipw,
    const float* __restrict__ opw, bf16_t* __restrict__ win, bf16_t* __restrict__ wout) {
  int i = blockIdx.x * 256 + threadIdx.x;
  const int n1 = DINPROJP * DMODEL;
  if (i < n1) {
    int row = i >> 9, col = i & (DMODEL - 1);
    float v = (row < DINPROJ) ? ipw[(size_t)row * DMODEL + col] : 0.f;
    win[i] = __float2bfloat16(v);
  } else {
    int j = i - n1;
    if (j < DMODEL * DINNER) wout[j] = __float2bfloat16(opw[j]);
  }
}

// ---------------- residual add + RMSNorm (512 cols), bf16 out ----------------
__global__ __launch_bounds__(128) void prenorm_kernel(const float* __restrict__ h,
    float* __restrict__ res, const float* __restrict__ w, bf16_t* __restrict__ xn) {
  int row = blockIdx.x;
  int tid = threadIdx.x;        // 128 threads, one float4 each (512 cols)
  const float4* h4 = (const float4*)(h + (size_t)row * DMODEL);
  float4* r4 = (float4*)(res + (size_t)row * DMODEL);
  float4 v = r4[tid];
  float4 a = h4[tid];
  v.x += a.x; v.y += a.y; v.z += a.z; v.w += a.w;
  r4[tid] = v;
  float ss = v.x * v.x + v.y * v.y + v.z * v.z + v.w * v.w;
  #pragma unroll
  for (int o = 32; o > 0; o >>= 1) ss += __shfl_down(ss, o);
  __shared__ float wred[2];
  if ((tid & 63) == 0) wred[tid >> 6] = ss;
  __syncthreads();
  float tot = wred[0] + wred[1];
  float scale = rsqrtf(tot / (float)DMODEL + EPSV);
  const float4* w4 = (const float4*)w;
  float4 wv = w4[tid];
  union { bf16_t b[4]; uint2 u; } pk;
  pk.b[0] = __float2bfloat16(v.x * scale * wv.x);
  pk.b[1] = __float2bfloat16(v.y * scale * wv.y);
  pk.b[2] = __float2bfloat16(v.z * scale * wv.z);
  pk.b[3] = __float2bfloat16(v.w * scale * wv.w);
  ((uint2*)(xn + (size_t)row * DMODEL))[tid] = pk.u;
}

// ---------------- bf16 MFMA GEMM: C[M,N] = A[M,K] * B[N,K]^T ----------------
// 128xBN tile, 4 waves; staging via global_load_lds width=16 (m93->m97 ladder step).
template<int BN>
__global__ __launch_bounds__(256) void gemm_bf16_bt(const bf16_t* __restrict__ A,
    const bf16_t* __restrict__ B, float* __restrict__ C, int M, int N, int K) {
  constexpr int JF = BN / 32;           // n-frags per wave
  __shared__ bf16_t As[128 * 32];
  __shared__ bf16_t Bs[BN * 32];
  int tid = threadIdx.x;
  int m0 = blockIdx.y * 128;
  int n0 = blockIdx.x * BN;
  int w = tid >> 6, lane = tid & 63;
  int wm = (w >> 1) * 64, wn = (w & 1) * (BN / 2);
  int l16 = lane & 15, lq = lane >> 4;
  floatx4 acc[4][JF];
  #pragma unroll
  for (int i = 0; i < 4; ++i)
    #pragma unroll
    for (int j = 0; j < JF; ++j)
      acc[i][j] = (floatx4){0.f, 0.f, 0.f, 0.f};
  int arow0 = tid >> 2, ak0 = (tid & 3) * 8;   // rows 0..63, k-seg 0..3
  const bf16_t* Abase = A + (size_t)m0 * K;
  const bf16_t* Bbase = B + (size_t)n0 * K;
  bf16_t* AsW = As + (w << 9);          // wave-uniform LDS bases (lane*16B appended by HW)
  bf16_t* BsW = Bs + (w << 9);
  for (int k0 = 0; k0 < K; k0 += 32) {
    __syncthreads();                    // previous iteration's LDS readers done
    gload_lds16(Abase + (size_t)arow0 * K + k0 + ak0, AsW);
    gload_lds16(Abase + (size_t)(arow0 + 64) * K + k0 + ak0, AsW + 2048);
    gload_lds16(Bbase + (size_t)arow0 * K + k0 + ak0, BsW);
    if (BN == 128)
      gload_lds16(Bbase + (size_t)(arow0 + 64) * K + k0 + ak0, BsW + 2048);
    __syncthreads();                    // drains vmcnt -> staged data visible
    bf16x8 af[4], bfr[JF];
    #pragma unroll
    for (int i = 0; i < 4; ++i)
      af[i] = *(const bf16x8*)(As + (wm + i * 16 + l16) * 32 + lq * 8);
    #pragma unroll
    for (int j = 0; j < JF; ++j)
      bfr[j] = *(const bf16x8*)(Bs + (wn + j * 16 + l16) * 32 + lq * 8);
    #pragma unroll
    for (int i = 0; i < 4; ++i)
      #pragma unroll
      for (int j = 0; j < JF; ++j)
        acc[i][j] = __builtin_amdgcn_mfma_f32_16x16x32_bf16(af[i], bfr[j], acc[i][j], 0, 0, 0);
  }
  #pragma unroll
  for (int i = 0; i < 4; ++i) {
    #pragma unroll
    for (int j = 0; j < JF; ++j) {
      int n = n0 + wn + j * 16 + l16;
      if (n < N) {
        int mb = m0 + wm + i * 16 + lq * 4;
        #pragma unroll
        for (int r = 0; r < 4; ++r)
          C[(size_t)(mb + r) * N + n] = acc[i][j][r];
      }
    }
  }
}

// ---------------- fused causal conv (width 4) + silu + dt/dA ----------------
// 4 consecutive timesteps per block via 7-row register sliding window.
__global__ __launch_bounds__(320) void convdt_kernel(const float* __restrict__ zx,
    const float* __restrict__ cw, const float* __restrict__ cb,
    const float* __restrict__ dt_bias, const float* __restrict__ A_log,
    float* __restrict__ out, float* __restrict__ dt, float* __restrict__ dA) {
  int bl0 = blockIdx.x * 4;                    // 4 consecutive rows, same sequence (SEQ%4==0)
  int t0 = bl0 % SEQ;
  int tid = threadIdx.x;                       // 0..319
  int c = tid * 4;
  const float* base = zx + (size_t)bl0 * DINPROJ + DINNER + c;
  float4 v[7];
  #pragma unroll
  for (int k = 0; k < 7; ++k) {
    int tt = t0 + k - 3;
    if (tt >= 0)
      v[k] = *(const float4*)(base + (ptrdiff_t)(k - 3) * DINPROJ);
    else
      v[k] = make_float4(0.f, 0.f, 0.f, 0.f);
  }
  float4 w0 = *(const float4*)(cw + (size_t)(c + 0) * 4);
  float4 w1 = *(const float4*)(cw + (size_t)(c + 1) * 4);
  float4 w2 = *(const float4*)(cw + (size_t)(c + 2) * 4);
  float4 w3 = *(const float4*)(cw + (size_t)(c + 3) * 4);
  float4 bias = *(const float4*)(cb + c);
  const float* w0f = (const float*)&w0;
  const float* w1f = (const float*)&w1;
  const float* w2f = (const float*)&w2;
  const float* w3f = (const float*)&w3;
  #pragma unroll
  for (int j = 0; j < 4; ++j) {
    float4 acc = bias;
    #pragma unroll
    for (int k = 0; k < 4; ++k) {
      float4 vv = v[j + k];
      acc.x += vv.x * w0f[k];
      acc.y += vv.y * w1f[k];
      acc.z += vv.z * w2f[k];
      acc.w += vv.w * w3f[k];
    }
    float4 o;
    o.x = siluf(acc.x); o.y = siluf(acc.y); o.z = siluf(acc.z); o.w = siluf(acc.w);
    *(float4*)(out + (size_t)(bl0 + j) * CONVDIM + c) = o;
  }
  if (tid < 64) {
    int j = tid >> 4, h = tid & 15;
    int bl = bl0 + j;
    float vv = zx[(size_t)bl * DINPROJ + (DINNER + CONVDIM) + h] + dt_bias[h];
    float sp = fmaxf(vv, 0.f) + log1pf(expf(-fabsf(vv)));
    float Ah = -expf(A_log[h]);
    dt[bl * NHEADS + h] = sp;
    dA[bl * NHEADS + h] = expf(sp * Ah);
  }
}

// ---------------- chunked SSD scan, pass 1: LDS-staged local scan ----------------
__global__ __launch_bounds__(256) void scan_local_kernel(const float* __restrict__ conv,
    const float* __restrict__ dtb, const float* __restrict__ dAb,
    const float* __restrict__ Dp, float* __restrict__ y,
    float* __restrict__ state, float* __restrict__ chunkprod) {
  int c = blockIdx.x;
  int bh = blockIdx.y;
  int b = bh >> 4, h = bh & 15;
  int tid = threadIdx.x;
  int s = tid >> 6;               // wave id: n-slice [32s, 32s+32)
  int p = tid & 63;               // lane = headdim index
  float hs[32];
  #pragma unroll
  for (int j = 0; j < 32; ++j) hs[j] = 0.f;
  float Dh = Dp[h];
  float prod = 1.f;
  __shared__ float BC[8][256];    // [tc][0..127]=B, [128..255]=C
  __shared__ float xs[8][64];
  __shared__ float dtA[16];       // [0..7]=dt, [8..15]=dA
  __shared__ float yred[8][4][64];
  const int tstart = c * CH;
  const size_t row0 = (size_t)(b * SEQ + tstart);

  // staging index precompute
  int i0 = tid, i1 = tid + 256;                 // BC float4 slots
  int bct0 = i0 >> 6, bco0 = (i0 & 63) * 4;
  int bct1 = i1 >> 6, bco1 = (i1 & 63) * 4;
  int xt = tid >> 4, xo = (tid & 15) * 4;       // xs float4 slots (tid<128)

  float4 r0, r1, rx = make_float4(0.f, 0.f, 0.f, 0.f);
  float rsc = 0.f;
  {
    // prologue: load group 0
    size_t rb = row0 * CONVDIM + DINNER;
    r0 = *(const float4*)(conv + rb + (size_t)bct0 * CONVDIM + bco0);
    r1 = *(const float4*)(conv + rb + (size_t)bct1 * CONVDIM + bco1);
    if (tid < 128) rx = *(const float4*)(conv + (row0 + xt) * CONVDIM + h * HEADDIM + xo);
    else if (tid < 136) rsc = dtb[(row0 + (tid - 128)) * NHEADS + h];
    else if (tid < 144) rsc = dAb[(row0 + (tid - 136)) * NHEADS + h];
  }

  for (int g = 0; g < CH / 8; ++g) {
    __syncthreads();              // previous iteration's LDS readers done
    *(float4*)&BC[bct0][bco0] = r0;
    *(float4*)&BC[bct1][bco1] = r1;
    if (tid < 128) *(float4*)&xs[xt][xo] = rx;
    else if (tid < 144) dtA[tid - 128] = rsc;
    __syncthreads();
    if (g + 1 < CH / 8) {
      size_t rb = (row0 + (g + 1) * 8) * CONVDIM + DINNER;
      r0 = *(const float4*)(conv + rb + (size_t)bct0 * CONVDIM + bco0);
      r1 = *(const float4*)(conv + rb + (size_t)bct1 * CONVDIM + bco1);
      if (tid < 128) rx = *(const float4*)(conv + (row0 + (g + 1) * 8 + xt) * CONVDIM + h * HEADDIM + xo);
      else if (tid < 136) rsc = dtb[(row0 + (g + 1) * 8 + (tid - 128)) * NHEADS + h];
      else if (tid < 144) rsc = dAb[(row0 + (g + 1) * 8 + (tid - 136)) * NHEADS + h];
    }
    #pragma unroll
    for (int tc = 0; tc < 8; ++tc) {
      float x = xs[tc][p];
      float dtv = dtA[tc];
      float dAv = dtA[8 + tc];
      float dtx = dtv * x;
      prod *= dAv;
      const float4* Bq = (const float4*)&BC[tc][s * 32];
      const float4* Cq = (const float4*)&BC[tc][128 + s * 32];
      float y0 = 0.f, y1 = 0.f, y2 = 0.f, y3 = 0.f;
      #pragma unroll
      for (int q = 0; q < 8; ++q) {
        float4 Bv = Bq[q];
        float4 Cv = Cq[q];
        hs[q * 4 + 0] = dAv * hs[q * 4 + 0] + dtx * Bv.x; y0 += hs[q * 4 + 0] * Cv.x;
        hs[q * 4 + 1] = dAv * hs[q * 4 + 1] + dtx * Bv.y; y1 += hs[q * 4 + 1] * Cv.y;
        hs[q * 4 + 2] = dAv * hs[q * 4 + 2] + dtx * Bv.z; y2 += hs[q * 4 + 2] * Cv.z;
        hs[q * 4 + 3] = dAv * hs[q * 4 + 3] + dtx * Bv.w; y3 += hs[q * 4 + 3] * Cv.w;
      }
      float yp = (y0 + y1) + (y2 + y3);
      if (s == 0) yp += Dh * x;
      yred[tc][s][p] = yp;
    }
    __syncthreads();
    for (int i = tid; i < 512; i += 256) {
      int tc = i >> 6, pp = i & 63;
      float v = yred[tc][0][pp] + yred[tc][1][pp] + yred[tc][2][pp] + yred[tc][3][pp];
      y[((size_t)(row0 + g * 8 + tc) * NHEADS + h) * HEADDIM + pp] = v;
    }
  }
  size_t sbase = ((size_t)bh * NCH + c) * STATESZ;
  #pragma unroll
  for (int j = 0; j < 32; ++j)
    state[sbase + (size_t)(s * 32 + j) * HEADDIM + p] = hs[j];
  if (tid == 0) chunkprod[bh * NCH + c] = prod;
}

// ---------------- inter-chunk state recurrence: H_in[c] = P[c-1]*H_in[c-1] + S[c-1] ----------------
__global__ __launch_bounds__(256) void state_combine_kernel(float* __restrict__ state,
    const float* __restrict__ cprod) {
  int bh = blockIdx.y;
  int sl = blockIdx.x;            // slice 0..7 (1024 floats each)
  int tid = threadIdx.x;
  float4* slab = (float4*)(state + (size_t)bh * NCH * STATESZ) + sl * 256 + tid;
  const float* pc = cprod + bh * NCH;
  float4 H = make_float4(0.f, 0.f, 0.f, 0.f);
  for (int c = 1; c < NCH; ++c) {
    float P = pc[c - 1];
    float4* sp = slab + (size_t)(c - 1) * (STATESZ / 4);
    float4 S = *sp;
    H.x = P * H.x + S.x; H.y = P * H.y + S.y;
    H.z = P * H.z + S.z; H.w = P * H.w + S.w;
    *sp = H;
  }
}

// ---------------- pass 2: y[t] += (cumA[t]*C_t) . H_in  (per chunk c>=1) ----------------
__global__ __launch_bounds__(256) void ycorr_kernel(const float* __restrict__ conv,
    const float* __restrict__ dAb, const float* __restrict__ state,
    float* __restrict__ y) {
  int c = blockIdx.x + 1;
  int bh = blockIdx.y;
  int b = bh >> 4, h = bh & 15;
  int tid = threadIdx.x;
  __shared__ float Cs[CH][DSTATE];   // 48KB, cumA-prescaled C rows
  __shared__ float cA[CH];
  const int tstart = c * CH;

  // inclusive prefix product of dA within chunk
  if (tid < CH) cA[tid] = dAb[((size_t)(b * SEQ + tstart + tid)) * NHEADS + h];
  __syncthreads();
  for (int off = 1; off < CH; off <<= 1) {
    float tmp = 1.f;
    if (tid < CH && tid >= off) tmp = cA[tid - off];
    __syncthreads();
    if (tid < CH) cA[tid] *= tmp;
    __syncthreads();
  }

  // stage C (scaled): 3072 float4 slots, coalesced (wave covers 2 rows per step)
  const float* Cg = conv + (size_t)(b * SEQ + tstart) * CONVDIM + DINNER + DSTATE;
  #pragma unroll
  for (int j = 0; j < 12; ++j) {
    int idx = j * 256 + tid;
    int row = idx >> 5, col4 = (idx & 31) * 4;
    float4 v = *(const float4*)(Cg + (size_t)row * CONVDIM + col4);
    float a = cA[row];
    v.x *= a; v.y *= a; v.z *= a; v.w *= a;
    *(float4*)&Cs[row][col4] = v;
  }
  __syncthreads();

  // product: thread (s,p) owns rows t = s+4i, i=0..23
  int s = tid >> 6, p = tid & 63;
  const float* Hb = state + ((size_t)bh * NCH + (c - 1)) * STATESZ + p;
  float acc[CH / 4];
  #pragma unroll
  for (int i = 0; i < CH / 4; ++i) acc[i] = 0.f;
  for (int n = 0; n < DSTATE; n += 4) {
    float h0 = Hb[(size_t)(n + 0) * HEADDIM];
    float h1 = Hb[(size_t)(n + 1) * HEADDIM];
    float h2 = Hb[(size_t)(n + 2) * HEADDIM];
    float h3 = Hb[(size_t)(n + 3) * HEADDIM];
    #pragma unroll
    for (int i = 0; i < CH / 4; ++i) {
      int tt = s + i * 4;
      float4 Cv = *(const float4*)&Cs[tt][n];   // wave-broadcast, conflict-free
      acc[i] += Cv.x * h0 + Cv.y * h1 + Cv.z * h2 + Cv.w * h3;
    }
  }
  #pragma unroll
  for (int i = 0; i < CH / 4; ++i) {
    int tt = s + i * 4;
    size_t yi = ((size_t)(b * SEQ + tstart + tt) * NHEADS + h) * HEADDIM + p;
    y[yi] += acc[i];
  }
}

// ---------------- gated RMSNorm over 1024, bf16 out ----------------
__global__ __launch_bounds__(256) void gated_norm_kernel(const float* __restrict__ y,
    const float* __restrict__ zx, const float* __restrict__ gw, bf16_t* __restrict__ out) {
  int row = blockIdx.x;
  int tid = threadIdx.x;
  const float4* y4 = (const float4*)(y + (size_t)row * DINNER);
  const float4* z4 = (const float4*)(zx + (size_t)row * DINPROJ);
  float4 yv = y4[tid];
  float4 zv = z4[tid];
  float4 g;
  g.x = yv.x * siluf(zv.x); g.y = yv.y * siluf(zv.y);
  g.z = yv.z * siluf(zv.z); g.w = yv.w * siluf(zv.w);
  float ss = g.x * g.x + g.y * g.y + g.z * g.z + g.w * g.w;
  #pragma unroll
  for (int o = 32; o > 0; o >>= 1) ss += __shfl_down(ss, o);
  __shared__ float red[4];
  if ((tid & 63) == 0) red[tid >> 6] = ss;
  __syncthreads();
  float tot = red[0] + red[1] + red[2] + red[3];
  float scale = rsqrtf(tot / (float)DINNER + EPSV);
  const float4* g4 = (const float4*)gw;
  float4 wv = g4[tid];
  union { bf16_t b[4]; uint2 u; } pk;
  pk.b[0] = __float2bfloat16(g.x * scale * wv.x);
  pk.b[1] = __float2bfloat16(g.y * scale * wv.y);
  pk.b[2] = __float2bfloat16(g.z * scale * wv.z);
  pk.b[3] = __float2bfloat16(g.w * scale * wv.w);
  ((uint2*)(out + (size_t)row * DINNER))[tid] = pk.u;
}

// ---------------- per-row loss: lse - logit[target] ----------------
__global__ __launch_bounds__(256) void rowloss_kernel(const float* __restrict__ logits,
    const int* __restrict__ targets, float* __restrict__ rl) {
  int row = blockIdx.x * 4 + (threadIdx.x >> 6);
  int lane = threadIdx.x & 63;
  const float* lr = logits + (size_t)row * VOCABSZ;
  float4 v = ((const float4*)lr)[lane];
  float mx = fmaxf(fmaxf(v.x, v.y), fmaxf(v.z, v.w));
  #pragma unroll
  for (int o = 32; o > 0; o >>= 1) mx = fmaxf(mx, __shfl_down(mx, o));
  mx = __shfl(mx, 0);
  float e = expf(v.x - mx) + expf(v.y - mx) + expf(v.z - mx) + expf(v.w - mx);
  #pragma unroll
  for (int o = 32; o > 0; o >>= 1) e += __shfl_down(e, o);
  if (lane == 0) {
    float lse = logf(e) + mx;
    rl[row] = lse - lr[targets[row]];
  }
}

__global__ __launch_bounds__(256) void loss_reduce_kernel(const float* __restrict__ rl,
    float* __restrict__ out) {
  int tid = threadIdx.x;
  float ssum = 0.f;
  for (int i = tid; i < NROWS; i += 256) ssum += rl[i];
  #pragma unroll
  for (int o = 32; o > 0; o >>= 1) ssum += __shfl_down(ssum, o);
  __shared__ float red[4];
  if ((tid & 63) == 0) red[tid >> 6] = ssum;
  __syncthreads();
  if (tid == 0) out[0] = (red[0] + red[1] + red[2] + red[3]) / (float)NROWS;
}

extern "C" void kernel_launch(void* const* d_in, const int* in_sizes, int n_in,
                              void* d_out, int out_size, void* d_ws, size_t ws_size,
                              hipStream_t stream) {
  const int*   tokens       = (const int*)d_in[0];
  const int*   targets      = (const int*)d_in[1];
  const float* embedding    = (const float*)d_in[2];
  const float* in_proj_w    = (const float*)d_in[3];
  const float* conv_w       = (const float*)d_in[4];
  const float* conv_b       = (const float*)d_in[5];
  const float* dt_bias      = (const float*)d_in[6];
  const float* A_log        = (const float*)d_in[7];
  const float* Dp           = (const float*)d_in[8];
  const float* gnorm_w      = (const float*)d_in[9];
  const float* out_proj_w   = (const float*)d_in[10];
  const float* block_norm_w = (const float*)d_in[11];
  const float* norm_f_w     = (const float*)d_in[12];
  float* out = (float*)d_out;

  float* ws = (float*)d_ws;
  size_t off = 0;
  float* hidden   = ws + off; off += (size_t)NROWS * DMODEL;
  float* residual = ws + off; off += (size_t)NROWS * DMODEL;
  float* zx       = ws + off; off += (size_t)NROWS * DINPROJ;
  float* convo    = ws + off; off += (size_t)NROWS * CONVDIM;
  float* dtb      = ws + off; off += (size_t)NROWS * NHEADS;
  float* dAb      = ws + off; off += (size_t)NROWS * NHEADS;
  float* ybuf     = ws + off; off += (size_t)NROWS * DINNER;
  float* cprod    = ws + off; off += (size_t)BATCH * NHEADS * NCH;
  float* rowloss  = ws + off; off += NROWS;
  bf16_t* w_in_bf  = (bf16_t*)(ws + off); off += (size_t)DINPROJP * DMODEL / 2;
  bf16_t* w_out_bf = (bf16_t*)(ws + off); off += (size_t)DMODEL * DINNER / 2;
  bf16_t* w_emb_bf = (bf16_t*)(ws + off); off += (size_t)VOCABSZ * DMODEL / 2;
  // union region: state (16.78M floats) vs bf16 activations (disjoint live ranges)
  float*  state  = ws + off;
  bf16_t* xn_bf  = (bf16_t*)(ws + off);   // live prenorm -> gemm1
  bf16_t* yn_bf  = (bf16_t*)(ws + off);   // live gated_norm -> gemm2
  off += (size_t)BATCH * NHEADS * NCH * STATESZ;

  embed_kernel<<<(NROWS * DMODEL + VOCABSZ * DMODEL) / 256, 256, 0, stream>>>(
      tokens, embedding, hidden, residual, w_emb_bf);

  const int cvt_total = DINPROJP * DMODEL + DMODEL * DINNER;
  for (int l = 0; l < NLAYER; ++l) {
    const float* ipw = in_proj_w + (size_t)l * DINPROJ * DMODEL;
    const float* cw  = conv_w + (size_t)l * CONVDIM * 4;
    const float* cb  = conv_b + (size_t)l * CONVDIM;
    const float* dtbias_l = dt_bias + (size_t)l * NHEADS;
    const float* alog_l   = A_log + (size_t)l * NHEADS;
    const float* D_l      = Dp + (size_t)l * NHEADS;
    const float* gw  = gnorm_w + (size_t)l * DINNER;
    const float* opw = out_proj_w + (size_t)l * DMODEL * DINNER;
    const float* bnw = block_norm_w + (size_t)l * DMODEL;

    cvt_weights_kernel<<<(cvt_total + 255) / 256, 256, 0, stream>>>(ipw, opw, w_in_bf, w_out_bf);
    prenorm_kernel<<<NROWS, 128, 0, stream>>>(hidden, residual, bnw, xn_bf);
    dim3 g1(DINPROJP / 128, NROWS / 128);
    gemm_bf16_bt<128><<<g1, 256, 0, stream>>>(xn_bf, w_in_bf, zx, NROWS, DINPROJ, DMODEL);
    convdt_kernel<<<NROWS / 4, 320, 0, stream>>>(zx, cw, cb, dtbias_l, alog_l, convo, dtb, dAb);
    scan_local_kernel<<<dim3(NCH, BATCH * NHEADS), 256, 0, stream>>>(
        convo, dtb, dAb, D_l, ybuf, state, cprod);
    state_combine_kernel<<<dim3(NCH, BATCH * NHEADS), 256, 0, stream>>>(state, cprod);
    ycorr_kernel<<<dim3(NCH - 1, BATCH * NHEADS), 256, 0, stream>>>(
        convo, dAb, state, ybuf);
    gated_norm_kernel<<<NROWS, 256, 0, stream>>>(ybuf, zx, gw, yn_bf);
    dim3 g2(DMODEL / 64, NROWS / 128);
    gemm_bf16_bt<64><<<g2, 256, 0, stream>>>(yn_bf, w_out_bf, hidden, NROWS, DMODEL, DINNER);
  }

  prenorm_kernel<<<NROWS, 128, 0, stream>>>(hidden, residual, norm_f_w, xn_bf);
  dim3 g3(VOCABSZ / 64, NROWS / 128);
  gemm_bf16_bt<64><<<g3, 256, 0, stream>>>(xn_bf, w_emb_bf, out, NROWS, VOCABSZ, DMODEL);
  rowloss_kernel<<<NROWS / 4, 256, 0, stream>>>(out, targets, rowloss);
  loss_reduce_kernel<<<1, 256, 0, stream>>>(rowloss, out + (size_t)(out_size - 1));
}

// Round 6
// 10536.989 us; speedup vs baseline: 1.7831x; 1.1279x over previous
//
#include <hip/hip_runtime.h>
#include <hip/hip_bf16.h>
#include <math.h>

#define BATCH   16
#define SEQ     768
#define DMODEL  512
#define DSTATE  128
#define DINNER  1024
#define NHEADS  16
#define HEADDIM 64
#define CONVDIM 1280            // DINNER + 2*DSTATE
#define DINPROJ 2320            // 2*DINNER + 2*DSTATE + NHEADS
#define DINPROJP 2432           // padded to multiple of 128 for GEMM tiles
#define NLAYER  28
#define VOCABSZ 256
#define NROWS   (BATCH*SEQ)     // 12288
#define EPSV    1e-5f
#define NCH     8               // chunks per sequence
#define CH      96              // SEQ / NCH
#define STATESZ (HEADDIM*DSTATE) // 8192 floats per (b,h,chunk)

typedef __hip_bfloat16 bf16_t;
typedef __attribute__((ext_vector_type(8))) __bf16 bf16x8;
typedef __attribute__((ext_vector_type(4))) float floatx4;

__device__ __forceinline__ float siluf(float v) { return v / (1.f + expf(-v)); }

// async global->LDS, 16B per lane; LDS dest = wave-uniform base + lane*16
__device__ __forceinline__ void gload_lds16(const bf16_t* g, bf16_t* l) {
  __builtin_amdgcn_global_load_lds(
      (const __attribute__((address_space(1))) unsigned int*)g,
      (__attribute__((address_space(3))) unsigned int*)l, 16, 0, 0);
}

// ---------------- embed + residual zero + embedding bf16 cvt, one dispatch ----------------
__global__ __launch_bounds__(256) void embed_kernel(const int* __restrict__ tok,
    const float* __restrict__ emb, float* __restrict__ hid, float* __restrict__ res,
    bf16_t* __restrict__ w_emb_bf) {
  int i = blockIdx.x * 256 + threadIdx.x;
  const int total = NROWS * DMODEL;
  if (i < total) {
    int r = i >> 9;               // / DMODEL
    int d = i & (DMODEL - 1);
    hid[i] = emb[(size_t)tok[r] * DMODEL + d];
    res[i] = 0.f;
  } else {
    int j = i - total;
    if (j < VOCABSZ * DMODEL) w_emb_bf[j] = __float2bfloat16(emb[j]);
  }
}

// ---------------- per-layer weight conversion, one dispatch ----------------
__global__ __launch_bounds__(256) void cvt_weights_kernel(const float* __restrict__ ipw,
    const float* __restrict__ opw, bf16_t* __restrict__ win, bf16_t* __restrict__ wout) {
  int i = blockIdx.x * 256 + threadIdx.x;
  const int n1 = DINPROJP * DMODEL;
  if (i < n1) {
    int row = i >> 9, col = i & (DMODEL - 1);
    float v = (row < DINPROJ) ? ipw[(size_t)row * DMODEL + col] : 0.f;
    win[i] = __float2bfloat16(v);
  } else {
    int j = i - n1;
    if (j < DMODEL * DINNER) wout[j] = __float2bfloat16(opw[j]);
  }
}

// ---------------- residual add + RMSNorm (512 cols), bf16 out ----------------
__global__ __launch_bounds__(128) void prenorm_kernel(const float* __restrict__ h,
    float* __restrict__ res, const float* __restrict__ w, bf16_t* __restrict__ xn) {
  int row = blockIdx.x;
  int tid = threadIdx.x;        // 128 threads, one float4 each (512 cols)
  const float4* h4 = (const float4*)(h + (size_t)row * DMODEL);
  float4* r4 = (float4*)(res + (size_t)row * DMODEL);
  float4 v = r4[tid];
  float4 a = h4[tid];
  v.x += a.x; v.y += a.y; v.z += a.z; v.w += a.w;
  r4[tid] = v;
  float ss = v.x * v.x + v.y * v.y + v.z * v.z + v.w * v.w;
  #pragma unroll
  for (int o = 32; o > 0; o >>= 1) ss += __shfl_down(ss, o);
  __shared__ float wred[2];
  if ((tid & 63) == 0) wred[tid >> 6] = ss;
  __syncthreads();
  float tot = wred[0] + wred[1];
  float scale = rsqrtf(tot / (float)DMODEL + EPSV);
  const float4* w4 = (const float4*)w;
  float4 wv = w4[tid];
  union { bf16_t b[4]; uint2 u; } pk;
  pk.b[0] = __float2bfloat16(v.x * scale * wv.x);
  pk.b[1] = __float2bfloat16(v.y * scale * wv.y);
  pk.b[2] = __float2bfloat16(v.z * scale * wv.z);
  pk.b[3] = __float2bfloat16(v.w * scale * wv.w);
  ((uint2*)(xn + (size_t)row * DMODEL))[tid] = pk.u;
}

// ---------------- bf16 MFMA GEMM: C[M,N] = A[M,K] * B[N,K]^T ----------------
// 128xBN tile, 4 waves; staging via global_load_lds width=16.
template<int BN>
__global__ __launch_bounds__(256) void gemm_bf16_bt(const bf16_t* __restrict__ A,
    const bf16_t* __restrict__ B, float* __restrict__ C, int M, int N, int K) {
  constexpr int JF = BN / 32;           // n-frags per wave
  __shared__ bf16_t As[128 * 32];
  __shared__ bf16_t Bs[BN * 32];
  int tid = threadIdx.x;
  int m0 = blockIdx.y * 128;
  int n0 = blockIdx.x * BN;
  int w = tid >> 6, lane = tid & 63;
  int wm = (w >> 1) * 64, wn = (w & 1) * (BN / 2);
  int l16 = lane & 15, lq = lane >> 4;
  floatx4 acc[4][JF];
  #pragma unroll
  for (int i = 0; i < 4; ++i)
    #pragma unroll
    for (int j = 0; j < JF; ++j)
      acc[i][j] = (floatx4){0.f, 0.f, 0.f, 0.f};
  int arow0 = tid >> 2, ak0 = (tid & 3) * 8;   // rows 0..63, k-seg 0..3
  const bf16_t* Abase = A + (size_t)m0 * K;
  const bf16_t* Bbase = B + (size_t)n0 * K;
  bf16_t* AsW = As + (w << 9);          // wave-uniform LDS bases (lane*16B appended by HW)
  bf16_t* BsW = Bs + (w << 9);
  for (int k0 = 0; k0 < K; k0 += 32) {
    __syncthreads();                    // previous iteration's LDS readers done
    gload_lds16(Abase + (size_t)arow0 * K + k0 + ak0, AsW);
    gload_lds16(Abase + (size_t)(arow0 + 64) * K + k0 + ak0, AsW + 2048);
    gload_lds16(Bbase + (size_t)arow0 * K + k0 + ak0, BsW);
    if (BN == 128)
      gload_lds16(Bbase + (size_t)(arow0 + 64) * K + k0 + ak0, BsW + 2048);
    __syncthreads();                    // drains vmcnt -> staged data visible
    bf16x8 af[4], bfr[JF];
    #pragma unroll
    for (int i = 0; i < 4; ++i)
      af[i] = *(const bf16x8*)(As + (wm + i * 16 + l16) * 32 + lq * 8);
    #pragma unroll
    for (int j = 0; j < JF; ++j)
      bfr[j] = *(const bf16x8*)(Bs + (wn + j * 16 + l16) * 32 + lq * 8);
    #pragma unroll
    for (int i = 0; i < 4; ++i)
      #pragma unroll
      for (int j = 0; j < JF; ++j)
        acc[i][j] = __builtin_amdgcn_mfma_f32_16x16x32_bf16(af[i], bfr[j], acc[i][j], 0, 0, 0);
  }
  #pragma unroll
  for (int i = 0; i < 4; ++i) {
    #pragma unroll
    for (int j = 0; j < JF; ++j) {
      int n = n0 + wn + j * 16 + l16;
      if (n < N) {
        int mb = m0 + wm + i * 16 + lq * 4;
        #pragma unroll
        for (int r = 0; r < 4; ++r)
          C[(size_t)(mb + r) * N + n] = acc[i][j][r];
      }
    }
  }
}

// ---------------- fused causal conv (width 4) + silu + dt/ldA ----------------
// NOTE: dA buffer now carries LOG dA (= softplus(dt)*A), consumed in log-space.
__global__ __launch_bounds__(320) void convdt_kernel(const float* __restrict__ zx,
    const float* __restrict__ cw, const float* __restrict__ cb,
    const float* __restrict__ dt_bias, const float* __restrict__ A_log,
    float* __restrict__ out, float* __restrict__ dt, float* __restrict__ ldA) {
  int bl0 = blockIdx.x * 4;                    // 4 consecutive rows, same sequence (SEQ%4==0)
  int t0 = bl0 % SEQ;
  int tid = threadIdx.x;                       // 0..319
  int c = tid * 4;
  const float* base = zx + (size_t)bl0 * DINPROJ + DINNER + c;
  float4 v[7];
  #pragma unroll
  for (int k = 0; k < 7; ++k) {
    int tt = t0 + k - 3;
    if (tt >= 0)
      v[k] = *(const float4*)(base + (ptrdiff_t)(k - 3) * DINPROJ);
    else
      v[k] = make_float4(0.f, 0.f, 0.f, 0.f);
  }
  float4 w0 = *(const float4*)(cw + (size_t)(c + 0) * 4);
  float4 w1 = *(const float4*)(cw + (size_t)(c + 1) * 4);
  float4 w2 = *(const float4*)(cw + (size_t)(c + 2) * 4);
  float4 w3 = *(const float4*)(cw + (size_t)(c + 3) * 4);
  float4 bias = *(const float4*)(cb + c);
  const float* w0f = (const float*)&w0;
  const float* w1f = (const float*)&w1;
  const float* w2f = (const float*)&w2;
  const float* w3f = (const float*)&w3;
  #pragma unroll
  for (int j = 0; j < 4; ++j) {
    float4 acc = bias;
    #pragma unroll
    for (int k = 0; k < 4; ++k) {
      float4 vv = v[j + k];
      acc.x += vv.x * w0f[k];
      acc.y += vv.y * w1f[k];
      acc.z += vv.z * w2f[k];
      acc.w += vv.w * w3f[k];
    }
    float4 o;
    o.x = siluf(acc.x); o.y = siluf(acc.y); o.z = siluf(acc.z); o.w = siluf(acc.w);
    *(float4*)(out + (size_t)(bl0 + j) * CONVDIM + c) = o;
  }
  if (tid < 64) {
    int j = tid >> 4, h = tid & 15;
    int bl = bl0 + j;
    float vv = zx[(size_t)bl * DINPROJ + (DINNER + CONVDIM) + h] + dt_bias[h];
    float sp = fmaxf(vv, 0.f) + log1pf(expf(-fabsf(vv)));
    float Ah = -expf(A_log[h]);
    dt[bl * NHEADS + h] = sp;
    ldA[bl * NHEADS + h] = sp * Ah;            // log dA (<= 0)
  }
}

// ---------------- MFMA chunked-SSD scan: per (b, chunk, 8-head group) ----------------
// G = C * B^T computed ONCE (B,C shared across heads), then per head:
// P[t][s] = exp(cum_t - cum_s) * dt_s * G[t][s]  (s<=t),  y = P@x + D*x,
// S = (exp(cumT-cum_t)*dt_t*B_t)^T @ x,  cprod = exp(cumT).
// All contractions use the same proven frag pattern as gemm_bf16_bt.
__global__ __launch_bounds__(512) void scan_mfma_kernel(const float* __restrict__ conv,
    const float* __restrict__ dtb, const float* __restrict__ ldAb,
    const float* __restrict__ Dp, float* __restrict__ y,
    float* __restrict__ state, float* __restrict__ chunkprod) {
  const int c  = blockIdx.x;                 // chunk
  const int b  = blockIdx.y >> 1;
  const int h0 = (blockIdx.y & 1) * 8;       // head group base
  const int tid  = threadIdx.x;              // 0..511
  const int w    = tid >> 6;                 // wave 0..7
  const int lane = tid & 63;
  const size_t row0 = (size_t)(b * SEQ + c * CH);

  __shared__ __align__(16) bf16_t Bb[96 * 136];    // B rows (t,n), padded
  __shared__ __align__(16) bf16_t Cb[96 * 136];    // C rows (t,n)
  __shared__ __align__(16) bf16_t Pl[96 * 104];    // P rows (t,s)
  __shared__ __align__(16) bf16_t xT[64 * 104];    // x^T (p,t)
  __shared__ __align__(16) bf16_t BTw[128 * 104];  // weighted B^T (n,t)
  __shared__ float ldas[8][96];
  __shared__ float dts[8][96];
  __shared__ float cums[8][96];
  __shared__ float wts[8][96];

  // ---- stage B, C (f32 -> bf16) ----
  for (int i = tid; i < 96 * 64; i += 512) {       // 64 float4 per row
    int t = i >> 6, q = i & 63;
    float4 v = *(const float4*)(conv + (row0 + t) * CONVDIM + DINNER + q * 4);
    if (q < 32) {
      int n = q * 4;
      bf16_t* d = Bb + t * 136 + n;
      d[0] = __float2bfloat16(v.x); d[1] = __float2bfloat16(v.y);
      d[2] = __float2bfloat16(v.z); d[3] = __float2bfloat16(v.w);
    } else {
      int n = q * 4 - 128;
      bf16_t* d = Cb + t * 136 + n;
      d[0] = __float2bfloat16(v.x); d[1] = __float2bfloat16(v.y);
      d[2] = __float2bfloat16(v.z); d[3] = __float2bfloat16(v.w);
    }
  }
  // ---- stage dt, ldA for 8 heads ----
  for (int i = tid; i < 768; i += 512) {
    int hh = i & 7, t = i >> 3;
    size_t gi = (row0 + t) * NHEADS + h0 + hh;
    dts[hh][t]  = dtb[gi];
    ldas[hh][t] = ldAb[gi];
  }
  __syncthreads();
  // ---- cum prefix (serial per head, 8 threads) ----
  if (tid < 8) {
    float cacc = 0.f;
    for (int t = 0; t < 96; ++t) { cacc += ldas[tid][t]; cums[tid][t] = cacc; }
  }
  __syncthreads();
  // ---- state weights + chunkprod ----
  for (int i = tid; i < 768; i += 512) {
    int hh = i & 7, t = i >> 3;
    wts[hh][t] = expf(cums[hh][95] - cums[hh][t]) * dts[hh][t];
  }
  if (tid < 8)
    chunkprod[(b * NHEADS + h0 + tid) * NCH + c] = expf(cums[tid][95]);

  // ---- G = C * B^T : 36 tiles of 16x16, wave w owns tiles {w, w+8, ...} ----
  floatx4 gacc[5];
  #pragma unroll
  for (int it = 0; it < 5; ++it) gacc[it] = (floatx4){0.f, 0.f, 0.f, 0.f};
  const int l16 = lane & 15, lk = (lane >> 4) << 3;
  #pragma unroll
  for (int it = 0; it < 5; ++it) {
    int tt = w + it * 8;
    int ti = (tt < 36) ? (tt / 6) : 0;
    int si = (tt < 36) ? (tt % 6) : 0;
    #pragma unroll
    for (int ks = 0; ks < 4; ++ks) {
      bf16x8 a = *(const bf16x8*)(Cb + (ti * 16 + l16) * 136 + ks * 32 + lk);
      bf16x8 bb = *(const bf16x8*)(Bb + (si * 16 + l16) * 136 + ks * 32 + lk);
      gacc[it] = __builtin_amdgcn_mfma_f32_16x16x32_bf16(a, bb, gacc[it], 0, 0, 0);
    }
  }

  // ---- per-head: build xT, BTw, P; then PX and S MFMA ----
  for (int hh = 0; hh < 8; ++hh) {
    __syncthreads();                    // prev head's MFMA readers done
    // x^T (p,t) bf16
    for (int i = tid; i < 6144; i += 512) {
      int t = i >> 6, p = i & 63;
      float xv = conv[(row0 + t) * CONVDIM + (h0 + hh) * HEADDIM + p];
      xT[p * 104 + t] = __float2bfloat16(xv);
    }
    // weighted B^T (n,t) bf16
    for (int i = tid; i < 128 * 96; i += 512) {
      int n = i / 96, t = i - n * 96;
      float bv = __bfloat162float(Bb[t * 136 + n]);
      BTw[n * 104 + t] = __float2bfloat16(wts[hh][t] * bv);
    }
    // P from G frags (wave-local registers)
    #pragma unroll
    for (int it = 0; it < 5; ++it) {
      int tt = w + it * 8;
      if (tt < 36) {
        int ti = tt / 6, si = tt % 6;
        int scol = si * 16 + l16;
        #pragma unroll
        for (int r = 0; r < 4; ++r) {
          int trow = ti * 16 + ((lane >> 4) << 2) + r;
          float pv = 0.f;
          if (scol <= trow)
            pv = expf(cums[hh][trow] - cums[hh][scol]) * dts[hh][scol] * gacc[it][r];
          Pl[trow * 104 + scol] = __float2bfloat16(pv);
        }
      }
    }
    __syncthreads();                    // builds visible
    float Dh = Dp[h0 + hh];
    // y = P @ x^T^T : 24 tiles (6 t x 4 p), 3 per wave
    #pragma unroll
    for (int it = 0; it < 3; ++it) {
      int tt = w + it * 8;
      int ti = tt >> 2, pi = tt & 3;
      floatx4 acc = (floatx4){0.f, 0.f, 0.f, 0.f};
      #pragma unroll
      for (int ks = 0; ks < 3; ++ks) {
        bf16x8 a = *(const bf16x8*)(Pl + (ti * 16 + l16) * 104 + ks * 32 + lk);
        bf16x8 bb = *(const bf16x8*)(xT + (pi * 16 + l16) * 104 + ks * 32 + lk);
        acc = __builtin_amdgcn_mfma_f32_16x16x32_bf16(a, bb, acc, 0, 0, 0);
      }
      int p = pi * 16 + l16;
      #pragma unroll
      for (int r = 0; r < 4; ++r) {
        int t = ti * 16 + ((lane >> 4) << 2) + r;
        float xg = conv[(row0 + t) * CONVDIM + (h0 + hh) * HEADDIM + p];
        y[((row0 + t) * NHEADS + h0 + hh) * HEADDIM + p] = acc[r] + Dh * xg;
      }
    }
    // S = BTw @ x : 32 tiles (8 n x 4 p), 4 per wave
    size_t sb = ((size_t)(b * NHEADS + h0 + hh) * NCH + c) * STATESZ;
    #pragma unroll
    for (int it = 0; it < 4; ++it) {
      int tt = w + it * 8;
      int ni = tt >> 2, pi = tt & 3;
      floatx4 acc = (floatx4){0.f, 0.f, 0.f, 0.f};
      #pragma unroll
      for (int ks = 0; ks < 3; ++ks) {
        bf16x8 a = *(const bf16x8*)(BTw + (ni * 16 + l16) * 104 + ks * 32 + lk);
        bf16x8 bb = *(const bf16x8*)(xT + (pi * 16 + l16) * 104 + ks * 32 + lk);
        acc = __builtin_amdgcn_mfma_f32_16x16x32_bf16(a, bb, acc, 0, 0, 0);
      }
      int p = pi * 16 + l16;
      #pragma unroll
      for (int r = 0; r < 4; ++r) {
        int n = ni * 16 + ((lane >> 4) << 2) + r;
        state[sb + (size_t)n * HEADDIM + p] = acc[r];
      }
    }
  }
}

// ---------------- inter-chunk state recurrence: H_in[c] = P[c-1]*H_in[c-1] + S[c-1] ----------------
__global__ __launch_bounds__(256) void state_combine_kernel(float* __restrict__ state,
    const float* __restrict__ cprod) {
  int bh = blockIdx.y;
  int sl = blockIdx.x;            // slice 0..7 (1024 floats each)
  int tid = threadIdx.x;
  float4* slab = (float4*)(state + (size_t)bh * NCH * STATESZ) + sl * 256 + tid;
  const float* pc = cprod + bh * NCH;
  float4 H = make_float4(0.f, 0.f, 0.f, 0.f);
  for (int c = 1; c < NCH; ++c) {
    float P = pc[c - 1];
    float4* sp = slab + (size_t)(c - 1) * (STATESZ / 4);
    float4 S = *sp;
    H.x = P * H.x + S.x; H.y = P * H.y + S.y;
    H.z = P * H.z + S.z; H.w = P * H.w + S.w;
    *sp = H;
  }
}

// ---------------- pass 2: y[t] += (cumA[t]*C_t) . H_in  (per chunk c>=1) ----------------
// cumA now derived from log-dA: additive prefix then exp.
__global__ __launch_bounds__(256) void ycorr_kernel(const float* __restrict__ conv,
    const float* __restrict__ ldAb, const float* __restrict__ state,
    float* __restrict__ y) {
  int c = blockIdx.x + 1;
  int bh = blockIdx.y;
  int b = bh >> 4, h = bh & 15;
  int tid = threadIdx.x;
  __shared__ float Cs[CH][DSTATE];   // 48KB, cumA-prescaled C rows
  __shared__ float cA[CH];
  const int tstart = c * CH;

  // inclusive prefix SUM of log dA, then exp
  if (tid < CH) cA[tid] = ldAb[((size_t)(b * SEQ + tstart + tid)) * NHEADS + h];
  __syncthreads();
  for (int off = 1; off < CH; off <<= 1) {
    float tmp = 0.f;
    if (tid < CH && tid >= off) tmp = cA[tid - off];
    __syncthreads();
    if (tid < CH) cA[tid] += tmp;
    __syncthreads();
  }
  if (tid < CH) cA[tid] = expf(cA[tid]);
  __syncthreads();

  // stage C (scaled): 3072 float4 slots, coalesced
  const float* Cg = conv + (size_t)(b * SEQ + tstart) * CONVDIM + DINNER + DSTATE;
  #pragma unroll
  for (int j = 0; j < 12; ++j) {
    int idx = j * 256 + tid;
    int row = idx >> 5, col4 = (idx & 31) * 4;
    float4 v = *(const float4*)(Cg + (size_t)row * CONVDIM + col4);
    float a = cA[row];
    v.x *= a; v.y *= a; v.z *= a; v.w *= a;
    *(float4*)&Cs[row][col4] = v;
  }
  __syncthreads();

  // product: thread (s,p) owns rows t = s+4i, i=0..23
  int s = tid >> 6, p = tid & 63;
  const float* Hb = state + ((size_t)bh * NCH + (c - 1)) * STATESZ + p;
  float acc[CH / 4];
  #pragma unroll
  for (int i = 0; i < CH / 4; ++i) acc[i] = 0.f;
  for (int n = 0; n < DSTATE; n += 4) {
    float h0 = Hb[(size_t)(n + 0) * HEADDIM];
    float h1 = Hb[(size_t)(n + 1) * HEADDIM];
    float h2 = Hb[(size_t)(n + 2) * HEADDIM];
    float h3 = Hb[(size_t)(n + 3) * HEADDIM];
    #pragma unroll
    for (int i = 0; i < CH / 4; ++i) {
      int tt = s + i * 4;
      float4 Cv = *(const float4*)&Cs[tt][n];   // wave-broadcast, conflict-free
      acc[i] += Cv.x * h0 + Cv.y * h1 + Cv.z * h2 + Cv.w * h3;
    }
  }
  #pragma unroll
  for (int i = 0; i < CH / 4; ++i) {
    int tt = s + i * 4;
    size_t yi = ((size_t)(b * SEQ + tstart + tt) * NHEADS + h) * HEADDIM + p;
    y[yi] += acc[i];
  }
}

// ---------------- gated RMSNorm over 1024, bf16 out ----------------
__global__ __launch_bounds__(256) void gated_norm_kernel(const float* __restrict__ y,
    const float* __restrict__ zx, const float* __restrict__ gw, bf16_t* __restrict__ out) {
  int row = blockIdx.x;
  int tid = threadIdx.x;
  const float4* y4 = (const float4*)(y + (size_t)row * DINNER);
  const float4* z4 = (const float4*)(zx + (size_t)row * DINPROJ);
  float4 yv = y4[tid];
  float4 zv = z4[tid];
  float4 g;
  g.x = yv.x * siluf(zv.x); g.y = yv.y * siluf(zv.y);
  g.z = yv.z * siluf(zv.z); g.w = yv.w * siluf(zv.w);
  float ss = g.x * g.x + g.y * g.y + g.z * g.z + g.w * g.w;
  #pragma unroll
  for (int o = 32; o > 0; o >>= 1) ss += __shfl_down(ss, o);
  __shared__ float red[4];
  if ((tid & 63) == 0) red[tid >> 6] = ss;
  __syncthreads();
  float tot = red[0] + red[1] + red[2] + red[3];
  float scale = rsqrtf(tot / (float)DINNER + EPSV);
  const float4* g4 = (const float4*)gw;
  float4 wv = g4[tid];
  union { bf16_t b[4]; uint2 u; } pk;
  pk.b[0] = __float2bfloat16(g.x * scale * wv.x);
  pk.b[1] = __float2bfloat16(g.y * scale * wv.y);
  pk.b[2] = __float2bfloat16(g.z * scale * wv.z);
  pk.b[3] = __float2bfloat16(g.w * scale * wv.w);
  ((uint2*)(out + (size_t)row * DINNER))[tid] = pk.u;
}

// ---------------- per-row loss: lse - logit[target] ----------------
__global__ __launch_bounds__(256) void rowloss_kernel(const float* __restrict__ logits,
    const int* __restrict__ targets, float* __restrict__ rl) {
  int row = blockIdx.x * 4 + (threadIdx.x >> 6);
  int lane = threadIdx.x & 63;
  const float* lr = logits + (size_t)row * VOCABSZ;
  float4 v = ((const float4*)lr)[lane];
  float mx = fmaxf(fmaxf(v.x, v.y), fmaxf(v.z, v.w));
  #pragma unroll
  for (int o = 32; o > 0; o >>= 1) mx = fmaxf(mx, __shfl_down(mx, o));
  mx = __shfl(mx, 0);
  float e = expf(v.x - mx) + expf(v.y - mx) + expf(v.z - mx) + expf(v.w - mx);
  #pragma unroll
  for (int o = 32; o > 0; o >>= 1) e += __shfl_down(e, o);
  if (lane == 0) {
    float lse = logf(e) + mx;
    rl[row] = lse - lr[targets[row]];
  }
}

__global__ __launch_bounds__(256) void loss_reduce_kernel(const float* __restrict__ rl,
    float* __restrict__ out) {
  int tid = threadIdx.x;
  float ssum = 0.f;
  for (int i = tid; i < NROWS; i += 256) ssum += rl[i];
  #pragma unroll
  for (int o = 32; o > 0; o >>= 1) ssum += __shfl_down(ssum, o);
  __shared__ float red[4];
  if ((tid & 63) == 0) red[tid >> 6] = ssum;
  __syncthreads();
  if (tid == 0) out[0] = (red[0] + red[1] + red[2] + red[3]) / (float)NROWS;
}

extern "C" void kernel_launch(void* const* d_in, const int* in_sizes, int n_in,
                              void* d_out, int out_size, void* d_ws, size_t ws_size,
                              hipStream_t stream) {
  const int*   tokens       = (const int*)d_in[0];
  const int*   targets      = (const int*)d_in[1];
  const float* embedding    = (const float*)d_in[2];
  const float* in_proj_w    = (const float*)d_in[3];
  const float* conv_w       = (const float*)d_in[4];
  const float* conv_b       = (const float*)d_in[5];
  const float* dt_bias      = (const float*)d_in[6];
  const float* A_log        = (const float*)d_in[7];
  const float* Dp           = (const float*)d_in[8];
  const float* gnorm_w      = (const float*)d_in[9];
  const float* out_proj_w   = (const float*)d_in[10];
  const float* block_norm_w = (const float*)d_in[11];
  const float* norm_f_w     = (const float*)d_in[12];
  float* out = (float*)d_out;

  float* ws = (float*)d_ws;
  size_t off = 0;
  float* hidden   = ws + off; off += (size_t)NROWS * DMODEL;
  float* residual = ws + off; off += (size_t)NROWS * DMODEL;
  float* zx       = ws + off; off += (size_t)NROWS * DINPROJ;
  float* convo    = ws + off; off += (size_t)NROWS * CONVDIM;
  float* dtb      = ws + off; off += (size_t)NROWS * NHEADS;
  float* ldAb     = ws + off; off += (size_t)NROWS * NHEADS;
  float* ybuf     = ws + off; off += (size_t)NROWS * DINNER;
  float* cprod    = ws + off; off += (size_t)BATCH * NHEADS * NCH;
  float* rowloss  = ws + off; off += NROWS;
  bf16_t* w_in_bf  = (bf16_t*)(ws + off); off += (size_t)DINPROJP * DMODEL / 2;
  bf16_t* w_out_bf = (bf16_t*)(ws + off); off += (size_t)DMODEL * DINNER / 2;
  bf16_t* w_emb_bf = (bf16_t*)(ws + off); off += (size_t)VOCABSZ * DMODEL / 2;
  // union region: state (16.78M floats) vs bf16 activations (disjoint live ranges)
  float*  state  = ws + off;
  bf16_t* xn_bf  = (bf16_t*)(ws + off);   // live prenorm -> gemm1
  bf16_t* yn_bf  = (bf16_t*)(ws + off);   // live gated_norm -> gemm2
  off += (size_t)BATCH * NHEADS * NCH * STATESZ;

  embed_kernel<<<(NROWS * DMODEL + VOCABSZ * DMODEL) / 256, 256, 0, stream>>>(
      tokens, embedding, hidden, residual, w_emb_bf);

  const int cvt_total = DINPROJP * DMODEL + DMODEL * DINNER;
  for (int l = 0; l < NLAYER; ++l) {
    const float* ipw = in_proj_w + (size_t)l * DINPROJ * DMODEL;
    const float* cw  = conv_w + (size_t)l * CONVDIM * 4;
    const float* cb  = conv_b + (size_t)l * CONVDIM;
    const float* dtbias_l = dt_bias + (size_t)l * NHEADS;
    const float* alog_l   = A_log + (size_t)l * NHEADS;
    const float* D_l      = Dp + (size_t)l * NHEADS;
    const float* gw  = gnorm_w + (size_t)l * DINNER;
    const float* opw = out_proj_w + (size_t)l * DMODEL * DINNER;
    const float* bnw = block_norm_w + (size_t)l * DMODEL;

    cvt_weights_kernel<<<(cvt_total + 255) / 256, 256, 0, stream>>>(ipw, opw, w_in_bf, w_out_bf);
    prenorm_kernel<<<NROWS, 128, 0, stream>>>(hidden, residual, bnw, xn_bf);
    dim3 g1(DINPROJP / 128, NROWS / 128);
    gemm_bf16_bt<128><<<g1, 256, 0, stream>>>(xn_bf, w_in_bf, zx, NROWS, DINPROJ, DMODEL);
    convdt_kernel<<<NROWS / 4, 320, 0, stream>>>(zx, cw, cb, dtbias_l, alog_l, convo, dtb, ldAb);
    scan_mfma_kernel<<<dim3(NCH, BATCH * 2), 512, 0, stream>>>(
        convo, dtb, ldAb, D_l, ybuf, state, cprod);
    state_combine_kernel<<<dim3(NCH, BATCH * NHEADS), 256, 0, stream>>>(state, cprod);
    ycorr_kernel<<<dim3(NCH - 1, BATCH * NHEADS), 256, 0, stream>>>(
        convo, ldAb, state, ybuf);
    gated_norm_kernel<<<NROWS, 256, 0, stream>>>(ybuf, zx, gw, yn_bf);
    dim3 g2(DMODEL / 64, NROWS / 128);
    gemm_bf16_bt<64><<<g2, 256, 0, stream>>>(yn_bf, w_out_bf, hidden, NROWS, DMODEL, DINNER);
  }

  prenorm_kernel<<<NROWS, 128, 0, stream>>>(hidden, residual, norm_f_w, xn_bf);
  dim3 g3(VOCABSZ / 64, NROWS / 128);
  gemm_bf16_bt<64><<<g3, 256, 0, stream>>>(xn_bf, w_emb_bf, out, NROWS, VOCABSZ, DMODEL);
  rowloss_kernel<<<NROWS / 4, 256, 0, stream>>>(out, targets, rowloss);
  loss_reduce_kernel<<<1, 256, 0, stream>>>(rowloss, out + (size_t)(out_size - 1));
}

// Round 8
// 9024.666 us; speedup vs baseline: 2.0819x; 1.1676x over previous
//
#include <hip/hip_runtime.h>
#include <hip/hip_bf16.h>
#include <math.h>

#define BATCH   16
#define SEQ     768
#define DMODEL  512
#define DSTATE  128
#define DINNER  1024
#define NHEADS  16
#define HEADDIM 64
#define CONVDIM 1280            // DINNER + 2*DSTATE
#define DINPROJ 2320            // 2*DINNER + 2*DSTATE + NHEADS
#define DINPROJP 2432           // padded to multiple of 128 for GEMM tiles
#define DTBASE  2304            // DINNER + CONVDIM: dt columns start here
#define NLAYER  28
#define VOCABSZ 256
#define NROWS   (BATCH*SEQ)     // 12288
#define EPSV    1e-5f
#define NCH     8               // chunks per sequence
#define CH      96              // SEQ / NCH
#define STATESZ (HEADDIM*DSTATE) // 8192 floats per (b,h,chunk)

typedef __hip_bfloat16 bf16_t;
typedef __attribute__((ext_vector_type(8))) __bf16 bf16x8;
typedef __attribute__((ext_vector_type(4))) float floatx4;

__device__ __forceinline__ float siluf(float v) { return v / (1.f + expf(-v)); }

// async global->LDS, 16B per lane; LDS dest = wave-uniform base + lane*16
__device__ __forceinline__ void gload_lds16(const bf16_t* g, bf16_t* l) {
  __builtin_amdgcn_global_load_lds(
      (const __attribute__((address_space(1))) unsigned int*)g,
      (__attribute__((address_space(3))) unsigned int*)l, 16, 0, 0);
}

// ---------------- embed + residual zero + embedding bf16 cvt, one dispatch ----------------
__global__ __launch_bounds__(256) void embed_kernel(const int* __restrict__ tok,
    const float* __restrict__ emb, float* __restrict__ hid, float* __restrict__ res,
    bf16_t* __restrict__ w_emb_bf) {
  int i = blockIdx.x * 256 + threadIdx.x;
  const int total = NROWS * DMODEL;
  if (i < total) {
    int r = i >> 9;               // / DMODEL
    int d = i & (DMODEL - 1);
    hid[i] = emb[(size_t)tok[r] * DMODEL + d];
    res[i] = 0.f;
  } else {
    int j = i - total;
    if (j < VOCABSZ * DMODEL) w_emb_bf[j] = __float2bfloat16(emb[j]);
  }
}

// ---------------- per-layer weight conversion, one dispatch ----------------
__global__ __launch_bounds__(256) void cvt_weights_kernel(const float* __restrict__ ipw,
    const float* __restrict__ opw, bf16_t* __restrict__ win, bf16_t* __restrict__ wout) {
  int i = blockIdx.x * 256 + threadIdx.x;
  const int n1 = DINPROJP * DMODEL;
  if (i < n1) {
    int row = i >> 9, col = i & (DMODEL - 1);
    float v = (row < DINPROJ) ? ipw[(size_t)row * DMODEL + col] : 0.f;
    win[i] = __float2bfloat16(v);
  } else {
    int j = i - n1;
    if (j < DMODEL * DINNER) wout[j] = __float2bfloat16(opw[j]);
  }
}

// ---------------- residual add + RMSNorm (512 cols), bf16 out ----------------
__global__ __launch_bounds__(128) void prenorm_kernel(const float* __restrict__ h,
    float* __restrict__ res, const float* __restrict__ w, bf16_t* __restrict__ xn) {
  int row = blockIdx.x;
  int tid = threadIdx.x;        // 128 threads, one float4 each (512 cols)
  const float4* h4 = (const float4*)(h + (size_t)row * DMODEL);
  float4* r4 = (float4*)(res + (size_t)row * DMODEL);
  float4 v = r4[tid];
  float4 a = h4[tid];
  v.x += a.x; v.y += a.y; v.z += a.z; v.w += a.w;
  r4[tid] = v;
  float ss = v.x * v.x + v.y * v.y + v.z * v.z + v.w * v.w;
  #pragma unroll
  for (int o = 32; o > 0; o >>= 1) ss += __shfl_down(ss, o);
  __shared__ float wred[2];
  if ((tid & 63) == 0) wred[tid >> 6] = ss;
  __syncthreads();
  float tot = wred[0] + wred[1];
  float scale = rsqrtf(tot / (float)DMODEL + EPSV);
  const float4* w4 = (const float4*)w;
  float4 wv = w4[tid];
  union { bf16_t b[4]; uint2 u; } pk;
  pk.b[0] = __float2bfloat16(v.x * scale * wv.x);
  pk.b[1] = __float2bfloat16(v.y * scale * wv.y);
  pk.b[2] = __float2bfloat16(v.z * scale * wv.z);
  pk.b[3] = __float2bfloat16(v.w * scale * wv.w);
  ((uint2*)(xn + (size_t)row * DMODEL))[tid] = pk.u;
}

// ---------------- bf16 MFMA GEMM: C[M,N] = A[M,K] * B[N,K]^T ----------------
// 128xBN tile, 4 waves; staging via global_load_lds width=16.
// TO = float or bf16_t output. aux (optional): f32 copy of cols >= DTBASE (dt path).
template<int BN, typename TO>
__global__ __launch_bounds__(256) void gemm_bf16_bt(const bf16_t* __restrict__ A,
    const bf16_t* __restrict__ B, TO* __restrict__ C, float* __restrict__ aux,
    int M, int N, int K) {
  constexpr int JF = BN / 32;           // n-frags per wave
  __shared__ bf16_t As[128 * 32];
  __shared__ bf16_t Bs[BN * 32];
  int tid = threadIdx.x;
  int m0 = blockIdx.y * 128;
  int n0 = blockIdx.x * BN;
  int w = tid >> 6, lane = tid & 63;
  int wm = (w >> 1) * 64, wn = (w & 1) * (BN / 2);
  int l16 = lane & 15, lq = lane >> 4;
  floatx4 acc[4][JF];
  #pragma unroll
  for (int i = 0; i < 4; ++i)
    #pragma unroll
    for (int j = 0; j < JF; ++j)
      acc[i][j] = (floatx4){0.f, 0.f, 0.f, 0.f};
  int arow0 = tid >> 2, ak0 = (tid & 3) * 8;   // rows 0..63, k-seg 0..3
  const bf16_t* Abase = A + (size_t)m0 * K;
  const bf16_t* Bbase = B + (size_t)n0 * K;
  bf16_t* AsW = As + (w << 9);          // wave-uniform LDS bases (lane*16B appended by HW)
  bf16_t* BsW = Bs + (w << 9);
  for (int k0 = 0; k0 < K; k0 += 32) {
    __syncthreads();                    // previous iteration's LDS readers done
    gload_lds16(Abase + (size_t)arow0 * K + k0 + ak0, AsW);
    gload_lds16(Abase + (size_t)(arow0 + 64) * K + k0 + ak0, AsW + 2048);
    gload_lds16(Bbase + (size_t)arow0 * K + k0 + ak0, BsW);
    if (BN == 128)
      gload_lds16(Bbase + (size_t)(arow0 + 64) * K + k0 + ak0, BsW + 2048);
    __syncthreads();                    // drains vmcnt -> staged data visible
    bf16x8 af[4], bfr[JF];
    #pragma unroll
    for (int i = 0; i < 4; ++i)
      af[i] = *(const bf16x8*)(As + (wm + i * 16 + l16) * 32 + lq * 8);
    #pragma unroll
    for (int j = 0; j < JF; ++j)
      bfr[j] = *(const bf16x8*)(Bs + (wn + j * 16 + l16) * 32 + lq * 8);
    #pragma unroll
    for (int i = 0; i < 4; ++i)
      #pragma unroll
      for (int j = 0; j < JF; ++j)
        acc[i][j] = __builtin_amdgcn_mfma_f32_16x16x32_bf16(af[i], bfr[j], acc[i][j], 0, 0, 0);
  }
  #pragma unroll
  for (int i = 0; i < 4; ++i) {
    #pragma unroll
    for (int j = 0; j < JF; ++j) {
      int n = n0 + wn + j * 16 + l16;
      if (n < N) {
        int mb = m0 + wm + i * 16 + lq * 4;
        #pragma unroll
        for (int r = 0; r < 4; ++r) {
          float vv = acc[i][j][r];
          if constexpr (sizeof(TO) == 2)
            C[(size_t)(mb + r) * N + n] = __float2bfloat16(vv);
          else
            C[(size_t)(mb + r) * N + n] = vv;
          if (aux && n >= DTBASE)
            aux[(size_t)(mb + r) * NHEADS + (n - DTBASE)] = vv;
        }
      }
    }
  }
}

// ---------------- fused causal conv (width 4) + silu + dt/ldA ----------------
// zx stored bf16; dt columns come from f32 dtcol (precision-critical path).
__global__ __launch_bounds__(320) void convdt_kernel(const bf16_t* __restrict__ zx,
    const float* __restrict__ dtcol, const float* __restrict__ cw,
    const float* __restrict__ cb, const float* __restrict__ dt_bias,
    const float* __restrict__ A_log, bf16_t* __restrict__ out,
    float* __restrict__ dt, float* __restrict__ ldA) {
  int bl0 = blockIdx.x * 4;                    // 4 consecutive rows, same sequence (SEQ%4==0)
  int t0 = bl0 % SEQ;
  int tid = threadIdx.x;                       // 0..319
  int c = tid * 4;
  const bf16_t* base = zx + (size_t)bl0 * DINPROJ + DINNER + c;
  float4 v[7];
  #pragma unroll
  for (int k = 0; k < 7; ++k) {
    int tt = t0 + k - 3;
    if (tt >= 0) {
      union { ushort4 u; bf16_t b[4]; } q;
      q.u = *(const ushort4*)(base + (ptrdiff_t)(k - 3) * DINPROJ);
      v[k] = make_float4(__bfloat162float(q.b[0]), __bfloat162float(q.b[1]),
                         __bfloat162float(q.b[2]), __bfloat162float(q.b[3]));
    } else {
      v[k] = make_float4(0.f, 0.f, 0.f, 0.f);
    }
  }
  float4 w0 = *(const float4*)(cw + (size_t)(c + 0) * 4);
  float4 w1 = *(const float4*)(cw + (size_t)(c + 1) * 4);
  float4 w2 = *(const float4*)(cw + (size_t)(c + 2) * 4);
  float4 w3 = *(const float4*)(cw + (size_t)(c + 3) * 4);
  float4 bias = *(const float4*)(cb + c);
  const float* w0f = (const float*)&w0;
  const float* w1f = (const float*)&w1;
  const float* w2f = (const float*)&w2;
  const float* w3f = (const float*)&w3;
  #pragma unroll
  for (int j = 0; j < 4; ++j) {
    float4 acc = bias;
    #pragma unroll
    for (int k = 0; k < 4; ++k) {
      float4 vv = v[j + k];
      acc.x += vv.x * w0f[k];
      acc.y += vv.y * w1f[k];
      acc.z += vv.z * w2f[k];
      acc.w += vv.w * w3f[k];
    }
    union { ushort4 u; bf16_t b[4]; } pk;
    pk.b[0] = __float2bfloat16(siluf(acc.x));
    pk.b[1] = __float2bfloat16(siluf(acc.y));
    pk.b[2] = __float2bfloat16(siluf(acc.z));
    pk.b[3] = __float2bfloat16(siluf(acc.w));
    *(ushort4*)(out + (size_t)(bl0 + j) * CONVDIM + c) = pk.u;
  }
  if (tid < 64) {
    int j = tid >> 4, h = tid & 15;
    int bl = bl0 + j;
    float vv = dtcol[(size_t)bl * NHEADS + h] + dt_bias[h];
    float sp = fmaxf(vv, 0.f) + log1pf(expf(-fabsf(vv)));
    float Ah = -expf(A_log[h]);
    dt[bl * NHEADS + h] = sp;
    ldA[bl * NHEADS + h] = sp * Ah;            // log dA (<= 0)
  }
}

// ---------------- MFMA chunked-SSD scan: per (b, chunk, 8-head group) ----------------
__global__ __launch_bounds__(512) void scan_mfma_kernel(const bf16_t* __restrict__ conv,
    const float* __restrict__ dtb, const float* __restrict__ ldAb,
    const float* __restrict__ Dp, float* __restrict__ y,
    float* __restrict__ state, float* __restrict__ chunkprod) {
  const int c  = blockIdx.x;                 // chunk
  const int b  = blockIdx.y >> 1;
  const int h0 = (blockIdx.y & 1) * 8;       // head group base
  const int tid  = threadIdx.x;              // 0..511
  const int w    = tid >> 6;                 // wave 0..7
  const int lane = tid & 63;
  const size_t row0 = (size_t)(b * SEQ + c * CH);

  __shared__ __align__(16) bf16_t Bb[96 * 136];    // B rows (t,n), padded
  __shared__ __align__(16) bf16_t Cb[96 * 136];    // C rows (t,n)
  __shared__ __align__(16) bf16_t Pl[96 * 104];    // P rows (t,s)
  __shared__ __align__(16) bf16_t xT[64 * 104];    // x^T (p,t)
  __shared__ __align__(16) bf16_t BTw[128 * 104];  // weighted B^T (n,t)
  __shared__ float ldas[8][96];
  __shared__ float dts[8][96];
  __shared__ float cums[8][96];
  __shared__ float wts[8][96];

  // ---- stage B, C (bf16 direct, 16B chunks) ----
  for (int i = tid; i < 96 * 32; i += 512) {
    int t = i >> 5, g = i & 31;
    bf16x8 v = *(const bf16x8*)(conv + (row0 + t) * CONVDIM + DINNER + g * 8);
    if (g < 16) *(bf16x8*)(Bb + t * 136 + g * 8) = v;
    else        *(bf16x8*)(Cb + t * 136 + (g - 16) * 8) = v;
  }
  // ---- stage dt, ldA for 8 heads ----
  for (int i = tid; i < 768; i += 512) {
    int hh = i & 7, t = i >> 3;
    size_t gi = (row0 + t) * NHEADS + h0 + hh;
    dts[hh][t]  = dtb[gi];
    ldas[hh][t] = ldAb[gi];
  }
  __syncthreads();
  // ---- cum prefix (serial per head, 8 threads) ----
  if (tid < 8) {
    float cacc = 0.f;
    for (int t = 0; t < 96; ++t) { cacc += ldas[tid][t]; cums[tid][t] = cacc; }
  }
  __syncthreads();
  // ---- state weights + chunkprod ----
  for (int i = tid; i < 768; i += 512) {
    int hh = i & 7, t = i >> 3;
    wts[hh][t] = expf(cums[hh][95] - cums[hh][t]) * dts[hh][t];
  }
  if (tid < 8)
    chunkprod[(b * NHEADS + h0 + tid) * NCH + c] = expf(cums[tid][95]);

  // ---- G = C * B^T : 36 tiles of 16x16, wave w owns tiles {w, w+8, ...} ----
  floatx4 gacc[5];
  #pragma unroll
  for (int it = 0; it < 5; ++it) gacc[it] = (floatx4){0.f, 0.f, 0.f, 0.f};
  const int l16 = lane & 15, lk = (lane >> 4) << 3;
  #pragma unroll
  for (int it = 0; it < 5; ++it) {
    int tt = w + it * 8;
    int ti = (tt < 36) ? (tt / 6) : 0;
    int si = (tt < 36) ? (tt % 6) : 0;
    #pragma unroll
    for (int ks = 0; ks < 4; ++ks) {
      bf16x8 a = *(const bf16x8*)(Cb + (ti * 16 + l16) * 136 + ks * 32 + lk);
      bf16x8 bb = *(const bf16x8*)(Bb + (si * 16 + l16) * 136 + ks * 32 + lk);
      gacc[it] = __builtin_amdgcn_mfma_f32_16x16x32_bf16(a, bb, gacc[it], 0, 0, 0);
    }
  }

  // ---- per-head: build xT, BTw, P; then PX and S MFMA ----
  for (int hh = 0; hh < 8; ++hh) {
    __syncthreads();                    // prev head's MFMA readers done
    // x^T (p,t): 16B global loads, bit-move LDS transpose stores (no bf16 conversions)
    for (int i = tid; i < 768; i += 512) {
      int t = i >> 3, p8 = (i & 7) * 8;
      union { bf16x8 v8; unsigned short s[8]; } u;
      u.v8 = *(const bf16x8*)(conv + (row0 + t) * CONVDIM + (h0 + hh) * HEADDIM + p8);
      #pragma unroll
      for (int r = 0; r < 8; ++r)
        ((unsigned short*)xT)[(p8 + r) * 104 + t] = u.s[r];
    }
    // weighted B^T (n,t) bf16
    for (int i = tid; i < 128 * 96; i += 512) {
      int n = i / 96, t = i - n * 96;
      float bv = __bfloat162float(Bb[t * 136 + n]);
      BTw[n * 104 + t] = __float2bfloat16(wts[hh][t] * bv);
    }
    // P from G frags (wave-local registers)
    #pragma unroll
    for (int it = 0; it < 5; ++it) {
      int tt = w + it * 8;
      if (tt < 36) {
        int ti = tt / 6, si = tt % 6;
        int scol = si * 16 + l16;
        #pragma unroll
        for (int r = 0; r < 4; ++r) {
          int trow = ti * 16 + ((lane >> 4) << 2) + r;
          float pv = 0.f;
          if (scol <= trow)
            pv = expf(cums[hh][trow] - cums[hh][scol]) * dts[hh][scol] * gacc[it][r];
          Pl[trow * 104 + scol] = __float2bfloat16(pv);
        }
      }
    }
    __syncthreads();                    // builds visible
    float Dh = Dp[h0 + hh];
    // y = P @ x : 24 tiles (6 t x 4 p), 3 per wave
    #pragma unroll
    for (int it = 0; it < 3; ++it) {
      int tt = w + it * 8;
      int ti = tt >> 2, pi = tt & 3;
      floatx4 acc = (floatx4){0.f, 0.f, 0.f, 0.f};
      #pragma unroll
      for (int ks = 0; ks < 3; ++ks) {
        bf16x8 a = *(const bf16x8*)(Pl + (ti * 16 + l16) * 104 + ks * 32 + lk);
        bf16x8 bb = *(const bf16x8*)(xT + (pi * 16 + l16) * 104 + ks * 32 + lk);
        acc = __builtin_amdgcn_mfma_f32_16x16x32_bf16(a, bb, acc, 0, 0, 0);
      }
      int p = pi * 16 + l16;
      #pragma unroll
      for (int r = 0; r < 4; ++r) {
        int t = ti * 16 + ((lane >> 4) << 2) + r;
        float xg = __bfloat162float(conv[(row0 + t) * CONVDIM + (h0 + hh) * HEADDIM + p]);
        y[((row0 + t) * NHEADS + h0 + hh) * HEADDIM + p] = acc[r] + Dh * xg;
      }
    }
    // S = BTw @ x : 32 tiles (8 n x 4 p), 4 per wave
    size_t sb = ((size_t)(b * NHEADS + h0 + hh) * NCH + c) * STATESZ;
    #pragma unroll
    for (int it = 0; it < 4; ++it) {
      int tt = w + it * 8;
      int ni = tt >> 2, pi = tt & 3;
      floatx4 acc = (floatx4){0.f, 0.f, 0.f, 0.f};
      #pragma unroll
      for (int ks = 0; ks < 3; ++ks) {
        bf16x8 a = *(const bf16x8*)(BTw + (ni * 16 + l16) * 104 + ks * 32 + lk);
        bf16x8 bb = *(const bf16x8*)(xT + (pi * 16 + l16) * 104 + ks * 32 + lk);
        acc = __builtin_amdgcn_mfma_f32_16x16x32_bf16(a, bb, acc, 0, 0, 0);
      }
      int p = pi * 16 + l16;
      #pragma unroll
      for (int r = 0; r < 4; ++r) {
        int n = ni * 16 + ((lane >> 4) << 2) + r;
        state[sb + (size_t)n * HEADDIM + p] = acc[r];
      }
    }
  }
}

// ---------------- inter-chunk state recurrence: H_in[c] = P[c-1]*H_in[c-1] + S[c-1] ----------------
__global__ __launch_bounds__(256) void state_combine_kernel(float* __restrict__ state,
    const float* __restrict__ cprod) {
  int bh = blockIdx.y;
  int sl = blockIdx.x;            // slice 0..7 (1024 floats each)
  int tid = threadIdx.x;
  float4* slab = (float4*)(state + (size_t)bh * NCH * STATESZ) + sl * 256 + tid;
  const float* pc = cprod + bh * NCH;
  float4 H = make_float4(0.f, 0.f, 0.f, 0.f);
  for (int c = 1; c < NCH; ++c) {
    float P = pc[c - 1];
    float4* sp = slab + (size_t)(c - 1) * (STATESZ / 4);
    float4 S = *sp;
    H.x = P * H.x + S.x; H.y = P * H.y + S.y;
    H.z = P * H.z + S.z; H.w = P * H.w + S.w;
    *sp = H;
  }
}

// ---------------- pass 2: y[t] += (cumA[t]*C_t) . H_in  (per chunk c>=1) ----------------
__global__ __launch_bounds__(256) void ycorr_kernel(const bf16_t* __restrict__ conv,
    const float* __restrict__ ldAb, const float* __restrict__ state,
    float* __restrict__ y) {
  int c = blockIdx.x + 1;
  int bh = blockIdx.y;
  int b = bh >> 4, h = bh & 15;
  int tid = threadIdx.x;
  __shared__ float Cs[CH][DSTATE];   // 48KB, cumA-prescaled C rows
  __shared__ float cA[CH];
  const int tstart = c * CH;

  // inclusive prefix SUM of log dA, then exp
  if (tid < CH) cA[tid] = ldAb[((size_t)(b * SEQ + tstart + tid)) * NHEADS + h];
  __syncthreads();
  for (int off = 1; off < CH; off <<= 1) {
    float tmp = 0.f;
    if (tid < CH && tid >= off) tmp = cA[tid - off];
    __syncthreads();
    if (tid < CH) cA[tid] += tmp;
    __syncthreads();
  }
  if (tid < CH) cA[tid] = expf(cA[tid]);
  __syncthreads();

  // stage C (scaled): bf16 16B loads -> f32 LDS
  const bf16_t* Cg = conv + (size_t)(b * SEQ + tstart) * CONVDIM + DINNER + DSTATE;
  #pragma unroll
  for (int j = 0; j < 6; ++j) {
    int idx = j * 256 + tid;                 // 1536 bf16x8 slots
    int row = idx >> 4, col8 = (idx & 15) * 8;
    bf16x8 v = *(const bf16x8*)(Cg + (size_t)row * CONVDIM + col8);
    float a = cA[row];
    float4 lo, hi;
    lo.x = a * (float)v[0]; lo.y = a * (float)v[1];
    lo.z = a * (float)v[2]; lo.w = a * (float)v[3];
    hi.x = a * (float)v[4]; hi.y = a * (float)v[5];
    hi.z = a * (float)v[6]; hi.w = a * (float)v[7];
    *(float4*)&Cs[row][col8] = lo;
    *(float4*)&Cs[row][col8 + 4] = hi;
  }
  __syncthreads();

  // product: thread (s,p) owns rows t = s+4i, i=0..23
  int s = tid >> 6, p = tid & 63;
  const float* Hb = state + ((size_t)bh * NCH + (c - 1)) * STATESZ + p;
  float acc[CH / 4];
  #pragma unroll
  for (int i = 0; i < CH / 4; ++i) acc[i] = 0.f;
  for (int n = 0; n < DSTATE; n += 4) {
    float h0 = Hb[(size_t)(n + 0) * HEADDIM];
    float h1 = Hb[(size_t)(n + 1) * HEADDIM];
    float h2 = Hb[(size_t)(n + 2) * HEADDIM];
    float h3 = Hb[(size_t)(n + 3) * HEADDIM];
    #pragma unroll
    for (int i = 0; i < CH / 4; ++i) {
      int tt = s + i * 4;
      float4 Cv = *(const float4*)&Cs[tt][n];   // wave-broadcast, conflict-free
      acc[i] += Cv.x * h0 + Cv.y * h1 + Cv.z * h2 + Cv.w * h3;
    }
  }
  #pragma unroll
  for (int i = 0; i < CH / 4; ++i) {
    int tt = s + i * 4;
    size_t yi = ((size_t)(b * SEQ + tstart + tt) * NHEADS + h) * HEADDIM + p;
    y[yi] += acc[i];
  }
}

// ---------------- gated RMSNorm over 1024, bf16 out ----------------
__global__ __launch_bounds__(256) void gated_norm_kernel(const float* __restrict__ y,
    const bf16_t* __restrict__ zx, const float* __restrict__ gw, bf16_t* __restrict__ out) {
  int row = blockIdx.x;
  int tid = threadIdx.x;
  const float4* y4 = (const float4*)(y + (size_t)row * DINNER);
  float4 yv = y4[tid];
  union { ushort4 u; bf16_t b[4]; } zq;
  zq.u = ((const ushort4*)(zx + (size_t)row * DINPROJ))[tid];
  float4 zv = make_float4(__bfloat162float(zq.b[0]), __bfloat162float(zq.b[1]),
                          __bfloat162float(zq.b[2]), __bfloat162float(zq.b[3]));
  float4 g;
  g.x = yv.x * siluf(zv.x); g.y = yv.y * siluf(zv.y);
  g.z = yv.z * siluf(zv.z); g.w = yv.w * siluf(zv.w);
  float ss = g.x * g.x + g.y * g.y + g.z * g.z + g.w * g.w;
  #pragma unroll
  for (int o = 32; o > 0; o >>= 1) ss += __shfl_down(ss, o);
  __shared__ float red[4];
  if ((tid & 63) == 0) red[tid >> 6] = ss;
  __syncthreads();
  float tot = red[0] + red[1] + red[2] + red[3];
  float scale = rsqrtf(tot / (float)DINNER + EPSV);
  const float4* g4 = (const float4*)gw;
  float4 wv = g4[tid];
  union { bf16_t b[4]; uint2 u; } pk;
  pk.b[0] = __float2bfloat16(g.x * scale * wv.x);
  pk.b[1] = __float2bfloat16(g.y * scale * wv.y);
  pk.b[2] = __float2bfloat16(g.z * scale * wv.z);
  pk.b[3] = __float2bfloat16(g.w * scale * wv.w);
  ((uint2*)(out + (size_t)row * DINNER))[tid] = pk.u;
}

// ---------------- per-row loss: lse - logit[target] ----------------
__global__ __launch_bounds__(256) void rowloss_kernel(const float* __restrict__ logits,
    const int* __restrict__ targets, float* __restrict__ rl) {
  int row = blockIdx.x * 4 + (threadIdx.x >> 6);
  int lane = threadIdx.x & 63;
  const float* lr = logits + (size_t)row * VOCABSZ;
  float4 v = ((const float4*)lr)[lane];
  float mx = fmaxf(fmaxf(v.x, v.y), fmaxf(v.z, v.w));
  #pragma unroll
  for (int o = 32; o > 0; o >>= 1) mx = fmaxf(mx, __shfl_down(mx, o));
  mx = __shfl(mx, 0);
  float e = expf(v.x - mx) + expf(v.y - mx) + expf(v.z - mx) + expf(v.w - mx);
  #pragma unroll
  for (int o = 32; o > 0; o >>= 1) e += __shfl_down(e, o);
  if (lane == 0) {
    float lse = logf(e) + mx;
    rl[row] = lse - lr[targets[row]];
  }
}

__global__ __launch_bounds__(256) void loss_reduce_kernel(const float* __restrict__ rl,
    float* __restrict__ out) {
  int tid = threadIdx.x;
  float ssum = 0.f;
  for (int i = tid; i < NROWS; i += 256) ssum += rl[i];
  #pragma unroll
  for (int o = 32; o > 0; o >>= 1) ssum += __shfl_down(ssum, o);
  __shared__ float red[4];
  if ((tid & 63) == 0) red[tid >> 6] = ssum;
  __syncthreads();
  if (tid == 0) out[0] = (red[0] + red[1] + red[2] + red[3]) / (float)NROWS;
}

extern "C" void kernel_launch(void* const* d_in, const int* in_sizes, int n_in,
                              void* d_out, int out_size, void* d_ws, size_t ws_size,
                              hipStream_t stream) {
  const int*   tokens       = (const int*)d_in[0];
  const int*   targets      = (const int*)d_in[1];
  const float* embedding    = (const float*)d_in[2];
  const float* in_proj_w    = (const float*)d_in[3];
  const float* conv_w       = (const float*)d_in[4];
  const float* conv_b       = (const float*)d_in[5];
  const float* dt_bias      = (const float*)d_in[6];
  const float* A_log        = (const float*)d_in[7];
  const float* Dp           = (const float*)d_in[8];
  const float* gnorm_w      = (const float*)d_in[9];
  const float* out_proj_w   = (const float*)d_in[10];
  const float* block_norm_w = (const float*)d_in[11];
  const float* norm_f_w     = (const float*)d_in[12];
  float* out = (float*)d_out;

  float* ws = (float*)d_ws;
  size_t off = 0;
  float* hidden   = ws + off; off += (size_t)NROWS * DMODEL;
  float* residual = ws + off; off += (size_t)NROWS * DMODEL;
  bf16_t* zx      = (bf16_t*)(ws + off); off += (size_t)NROWS * DINPROJ / 2;
  float* dtcol    = ws + off; off += (size_t)NROWS * NHEADS;
  bf16_t* convo   = (bf16_t*)(ws + off); off += (size_t)NROWS * CONVDIM / 2;
  float* dtb      = ws + off; off += (size_t)NROWS * NHEADS;
  float* ldAb     = ws + off; off += (size_t)NROWS * NHEADS;
  float* ybuf     = ws + off; off += (size_t)NROWS * DINNER;
  float* cprod    = ws + off; off += (size_t)BATCH * NHEADS * NCH;
  float* rowloss  = ws + off; off += NROWS;
  bf16_t* w_in_bf  = (bf16_t*)(ws + off); off += (size_t)DINPROJP * DMODEL / 2;
  bf16_t* w_out_bf = (bf16_t*)(ws + off); off += (size_t)DMODEL * DINNER / 2;
  bf16_t* w_emb_bf = (bf16_t*)(ws + off); off += (size_t)VOCABSZ * DMODEL / 2;
  // union region: state (16.78M floats) vs bf16 activations (disjoint live ranges)
  float*  state  = ws + off;
  bf16_t* xn_bf  = (bf16_t*)(ws + off);   // live prenorm -> gemm1
  bf16_t* yn_bf  = (bf16_t*)(ws + off);   // live gated_norm -> gemm2
  off += (size_t)BATCH * NHEADS * NCH * STATESZ;

  embed_kernel<<<(NROWS * DMODEL + VOCABSZ * DMODEL) / 256, 256, 0, stream>>>(
      tokens, embedding, hidden, residual, w_emb_bf);

  const int cvt_total = DINPROJP * DMODEL + DMODEL * DINNER;
  for (int l = 0; l < NLAYER; ++l) {
    const float* ipw = in_proj_w + (size_t)l * DINPROJ * DMODEL;
    const float* cw  = conv_w + (size_t)l * CONVDIM * 4;
    const float* cb  = conv_b + (size_t)l * CONVDIM;
    const float* dtbias_l = dt_bias + (size_t)l * NHEADS;
    const float* alog_l   = A_log + (size_t)l * NHEADS;
    const float* D_l      = Dp + (size_t)l * NHEADS;
    const float* gw  = gnorm_w + (size_t)l * DINNER;
    const float* opw = out_proj_w + (size_t)l * DMODEL * DINNER;
    const float* bnw = block_norm_w + (size_t)l * DMODEL;

    cvt_weights_kernel<<<(cvt_total + 255) / 256, 256, 0, stream>>>(ipw, opw, w_in_bf, w_out_bf);
    prenorm_kernel<<<NROWS, 128, 0, stream>>>(hidden, residual, bnw, xn_bf);
    dim3 g1(DINPROJP / 128, NROWS / 128);
    gemm_bf16_bt<128, bf16_t><<<g1, 256, 0, stream>>>(xn_bf, w_in_bf, zx, dtcol,
                                                      NROWS, DINPROJ, DMODEL);
    convdt_kernel<<<NROWS / 4, 320, 0, stream>>>(zx, dtcol, cw, cb, dtbias_l, alog_l,
                                                 convo, dtb, ldAb);
    scan_mfma_kernel<<<dim3(NCH, BATCH * 2), 512, 0, stream>>>(
        convo, dtb, ldAb, D_l, ybuf, state, cprod);
    state_combine_kernel<<<dim3(NCH, BATCH * NHEADS), 256, 0, stream>>>(state, cprod);
    ycorr_kernel<<<dim3(NCH - 1, BATCH * NHEADS), 256, 0, stream>>>(
        convo, ldAb, state, ybuf);
    gated_norm_kernel<<<NROWS, 256, 0, stream>>>(ybuf, zx, gw, yn_bf);
    dim3 g2(DMODEL / 64, NROWS / 128);
    gemm_bf16_bt<64, float><<<g2, 256, 0, stream>>>(yn_bf, w_out_bf, hidden, nullptr,
                                                    NROWS, DMODEL, DINNER);
  }

  prenorm_kernel<<<NROWS, 128, 0, stream>>>(hidden, residual, norm_f_w, xn_bf);
  dim3 g3(VOCABSZ / 64, NROWS / 128);
  gemm_bf16_bt<64, float><<<g3, 256, 0, stream>>>(xn_bf, w_emb_bf, out, nullptr,
                                                  NROWS, VOCABSZ, DMODEL);
  rowloss_kernel<<<NROWS / 4, 256, 0, stream>>>(out, targets, rowloss);
  loss_reduce_kernel<<<1, 256, 0, stream>>>(rowloss, out + (size_t)(out_size - 1));
}

// Round 9
// 7587.313 us; speedup vs baseline: 2.4762x; 1.1894x over previous
//
#include <hip/hip_runtime.h>
#include <hip/hip_bf16.h>
#include <math.h>

#define BATCH   16
#define SEQ     768
#define DMODEL  512
#define DSTATE  128
#define DINNER  1024
#define NHEADS  16
#define HEADDIM 64
#define CONVDIM 1280            // DINNER + 2*DSTATE
#define DINPROJ 2320            // 2*DINNER + 2*DSTATE + NHEADS
#define DINPROJP 2432           // padded to multiple of 128 for GEMM tiles
#define DTBASE  2304            // DINNER + CONVDIM: dt columns start here
#define NLAYER  28
#define VOCABSZ 256
#define NROWS   (BATCH*SEQ)     // 12288
#define EPSV    1e-5f
#define NCH     8               // chunks per sequence
#define CH      96              // SEQ / NCH
#define STATESZ (HEADDIM*DSTATE) // 8192 floats per (b,h,chunk)

typedef __hip_bfloat16 bf16_t;
typedef __attribute__((ext_vector_type(8))) __bf16 bf16x8;
typedef __attribute__((ext_vector_type(4))) float floatx4;

__device__ __forceinline__ float siluf(float v) { return v / (1.f + expf(-v)); }

// async global->LDS, 16B per lane; LDS dest = wave-uniform base + lane*16
__device__ __forceinline__ void gload_lds16(const bf16_t* g, bf16_t* l) {
  __builtin_amdgcn_global_load_lds(
      (const __attribute__((address_space(1))) unsigned int*)g,
      (__attribute__((address_space(3))) unsigned int*)l, 16, 0, 0);
}

// ---------------- embed + residual zero + embedding bf16 cvt, one dispatch ----------------
__global__ __launch_bounds__(256) void embed_kernel(const int* __restrict__ tok,
    const float* __restrict__ emb, float* __restrict__ hid, float* __restrict__ res,
    bf16_t* __restrict__ w_emb_bf) {
  int i = blockIdx.x * 256 + threadIdx.x;
  const int total = NROWS * DMODEL;
  if (i < total) {
    int r = i >> 9;               // / DMODEL
    int d = i & (DMODEL - 1);
    hid[i] = emb[(size_t)tok[r] * DMODEL + d];
    res[i] = 0.f;
  } else {
    int j = i - total;
    if (j < VOCABSZ * DMODEL) w_emb_bf[j] = __float2bfloat16(emb[j]);
  }
}

// ---------------- per-layer weight conversion, one dispatch ----------------
__global__ __launch_bounds__(256) void cvt_weights_kernel(const float* __restrict__ ipw,
    const float* __restrict__ opw, bf16_t* __restrict__ win, bf16_t* __restrict__ wout) {
  int i = blockIdx.x * 256 + threadIdx.x;
  const int n1 = DINPROJP * DMODEL;
  if (i < n1) {
    int row = i >> 9, col = i & (DMODEL - 1);
    float v = (row < DINPROJ) ? ipw[(size_t)row * DMODEL + col] : 0.f;
    win[i] = __float2bfloat16(v);
  } else {
    int j = i - n1;
    if (j < DMODEL * DINNER) wout[j] = __float2bfloat16(opw[j]);
  }
}

// ---------------- residual add + RMSNorm (512 cols), bf16 out ----------------
__global__ __launch_bounds__(128) void prenorm_kernel(const float* __restrict__ h,
    float* __restrict__ res, const float* __restrict__ w, bf16_t* __restrict__ xn) {
  int row = blockIdx.x;
  int tid = threadIdx.x;        // 128 threads, one float4 each (512 cols)
  const float4* h4 = (const float4*)(h + (size_t)row * DMODEL);
  float4* r4 = (float4*)(res + (size_t)row * DMODEL);
  float4 v = r4[tid];
  float4 a = h4[tid];
  v.x += a.x; v.y += a.y; v.z += a.z; v.w += a.w;
  r4[tid] = v;
  float ss = v.x * v.x + v.y * v.y + v.z * v.z + v.w * v.w;
  #pragma unroll
  for (int o = 32; o > 0; o >>= 1) ss += __shfl_down(ss, o);
  __shared__ float wred[2];
  if ((tid & 63) == 0) wred[tid >> 6] = ss;
  __syncthreads();
  float tot = wred[0] + wred[1];
  float scale = rsqrtf(tot / (float)DMODEL + EPSV);
  const float4* w4 = (const float4*)w;
  float4 wv = w4[tid];
  union { bf16_t b[4]; uint2 u; } pk;
  pk.b[0] = __float2bfloat16(v.x * scale * wv.x);
  pk.b[1] = __float2bfloat16(v.y * scale * wv.y);
  pk.b[2] = __float2bfloat16(v.z * scale * wv.z);
  pk.b[3] = __float2bfloat16(v.w * scale * wv.w);
  ((uint2*)(xn + (size_t)row * DMODEL))[tid] = pk.u;
}

// ---------------- bf16 MFMA GEMM: C[M,N] = A[M,K] * B[N,K]^T ----------------
// 128xBN tile, 4 waves; staging via global_load_lds width=16.
// TO = float or bf16_t output. aux (optional): f32 copy of cols >= DTBASE (dt path).
template<int BN, typename TO>
__global__ __launch_bounds__(256) void gemm_bf16_bt(const bf16_t* __restrict__ A,
    const bf16_t* __restrict__ B, TO* __restrict__ C, float* __restrict__ aux,
    int M, int N, int K) {
  constexpr int JF = BN / 32;           // n-frags per wave
  __shared__ bf16_t As[128 * 32];
  __shared__ bf16_t Bs[BN * 32];
  int tid = threadIdx.x;
  int m0 = blockIdx.y * 128;
  int n0 = blockIdx.x * BN;
  int w = tid >> 6, lane = tid & 63;
  int wm = (w >> 1) * 64, wn = (w & 1) * (BN / 2);
  int l16 = lane & 15, lq = lane >> 4;
  floatx4 acc[4][JF];
  #pragma unroll
  for (int i = 0; i < 4; ++i)
    #pragma unroll
    for (int j = 0; j < JF; ++j)
      acc[i][j] = (floatx4){0.f, 0.f, 0.f, 0.f};
  int arow0 = tid >> 2, ak0 = (tid & 3) * 8;   // rows 0..63, k-seg 0..3
  const bf16_t* Abase = A + (size_t)m0 * K;
  const bf16_t* Bbase = B + (size_t)n0 * K;
  bf16_t* AsW = As + (w << 9);          // wave-uniform LDS bases (lane*16B appended by HW)
  bf16_t* BsW = Bs + (w << 9);
  for (int k0 = 0; k0 < K; k0 += 32) {
    __syncthreads();                    // previous iteration's LDS readers done
    gload_lds16(Abase + (size_t)arow0 * K + k0 + ak0, AsW);
    gload_lds16(Abase + (size_t)(arow0 + 64) * K + k0 + ak0, AsW + 2048);
    gload_lds16(Bbase + (size_t)arow0 * K + k0 + ak0, BsW);
    if (BN == 128)
      gload_lds16(Bbase + (size_t)(arow0 + 64) * K + k0 + ak0, BsW + 2048);
    __syncthreads();                    // drains vmcnt -> staged data visible
    bf16x8 af[4], bfr[JF];
    #pragma unroll
    for (int i = 0; i < 4; ++i)
      af[i] = *(const bf16x8*)(As + (wm + i * 16 + l16) * 32 + lq * 8);
    #pragma unroll
    for (int j = 0; j < JF; ++j)
      bfr[j] = *(const bf16x8*)(Bs + (wn + j * 16 + l16) * 32 + lq * 8);
    #pragma unroll
    for (int i = 0; i < 4; ++i)
      #pragma unroll
      for (int j = 0; j < JF; ++j)
        acc[i][j] = __builtin_amdgcn_mfma_f32_16x16x32_bf16(af[i], bfr[j], acc[i][j], 0, 0, 0);
  }
  #pragma unroll
  for (int i = 0; i < 4; ++i) {
    #pragma unroll
    for (int j = 0; j < JF; ++j) {
      int n = n0 + wn + j * 16 + l16;
      if (n < N) {
        int mb = m0 + wm + i * 16 + lq * 4;
        #pragma unroll
        for (int r = 0; r < 4; ++r) {
          float vv = acc[i][j][r];
          if constexpr (sizeof(TO) == 2)
            C[(size_t)(mb + r) * N + n] = __float2bfloat16(vv);
          else
            C[(size_t)(mb + r) * N + n] = vv;
          if (aux && n >= DTBASE)
            aux[(size_t)(mb + r) * NHEADS + (n - DTBASE)] = vv;
        }
      }
    }
  }
}

// ---------------- fused causal conv (width 4) + silu + dt/ldA ----------------
// zx stored bf16; dt columns come from f32 dtcol (precision-critical path).
__global__ __launch_bounds__(320) void convdt_kernel(const bf16_t* __restrict__ zx,
    const float* __restrict__ dtcol, const float* __restrict__ cw,
    const float* __restrict__ cb, const float* __restrict__ dt_bias,
    const float* __restrict__ A_log, bf16_t* __restrict__ out,
    float* __restrict__ dt, float* __restrict__ ldA) {
  int bl0 = blockIdx.x * 4;                    // 4 consecutive rows, same sequence (SEQ%4==0)
  int t0 = bl0 % SEQ;
  int tid = threadIdx.x;                       // 0..319
  int c = tid * 4;
  const bf16_t* base = zx + (size_t)bl0 * DINPROJ + DINNER + c;
  float4 v[7];
  #pragma unroll
  for (int k = 0; k < 7; ++k) {
    int tt = t0 + k - 3;
    if (tt >= 0) {
      union { ushort4 u; bf16_t b[4]; } q;
      q.u = *(const ushort4*)(base + (ptrdiff_t)(k - 3) * DINPROJ);
      v[k] = make_float4(__bfloat162float(q.b[0]), __bfloat162float(q.b[1]),
                         __bfloat162float(q.b[2]), __bfloat162float(q.b[3]));
    } else {
      v[k] = make_float4(0.f, 0.f, 0.f, 0.f);
    }
  }
  float4 w0 = *(const float4*)(cw + (size_t)(c + 0) * 4);
  float4 w1 = *(const float4*)(cw + (size_t)(c + 1) * 4);
  float4 w2 = *(const float4*)(cw + (size_t)(c + 2) * 4);
  float4 w3 = *(const float4*)(cw + (size_t)(c + 3) * 4);
  float4 bias = *(const float4*)(cb + c);
  const float* w0f = (const float*)&w0;
  const float* w1f = (const float*)&w1;
  const float* w2f = (const float*)&w2;
  const float* w3f = (const float*)&w3;
  #pragma unroll
  for (int j = 0; j < 4; ++j) {
    float4 acc = bias;
    #pragma unroll
    for (int k = 0; k < 4; ++k) {
      float4 vv = v[j + k];
      acc.x += vv.x * w0f[k];
      acc.y += vv.y * w1f[k];
      acc.z += vv.z * w2f[k];
      acc.w += vv.w * w3f[k];
    }
    union { ushort4 u; bf16_t b[4]; } pk;
    pk.b[0] = __float2bfloat16(siluf(acc.x));
    pk.b[1] = __float2bfloat16(siluf(acc.y));
    pk.b[2] = __float2bfloat16(siluf(acc.z));
    pk.b[3] = __float2bfloat16(siluf(acc.w));
    *(ushort4*)(out + (size_t)(bl0 + j) * CONVDIM + c) = pk.u;
  }
  if (tid < 64) {
    int j = tid >> 4, h = tid & 15;
    int bl = bl0 + j;
    float vv = dtcol[(size_t)bl * NHEADS + h] + dt_bias[h];
    float sp = fmaxf(vv, 0.f) + log1pf(expf(-fabsf(vv)));
    float Ah = -expf(A_log[h]);
    dt[bl * NHEADS + h] = sp;
    ldA[bl * NHEADS + h] = sp * Ah;            // log dA (<= 0)
  }
}

// ---------------- MFMA chunked-SSD scan: per (b, chunk, 8-head group) ----------------
__global__ __launch_bounds__(512) void scan_mfma_kernel(const bf16_t* __restrict__ conv,
    const float* __restrict__ dtb, const float* __restrict__ ldAb,
    const float* __restrict__ Dp, float* __restrict__ y,
    float* __restrict__ state, float* __restrict__ chunkprod,
    float* __restrict__ cumb) {
  const int c  = blockIdx.x;                 // chunk
  const int b  = blockIdx.y >> 1;
  const int h0 = (blockIdx.y & 1) * 8;       // head group base
  const int tid  = threadIdx.x;              // 0..511
  const int w    = tid >> 6;                 // wave 0..7
  const int lane = tid & 63;
  const size_t row0 = (size_t)(b * SEQ + c * CH);

  __shared__ __align__(16) bf16_t Bb[96 * 136];    // B rows (t,n), padded
  __shared__ __align__(16) bf16_t Cb[96 * 136];    // C rows (t,n)
  __shared__ __align__(16) bf16_t Pl[96 * 104];    // P rows (t,s)
  __shared__ __align__(16) bf16_t xT[64 * 104];    // x^T (p,t)
  __shared__ __align__(16) bf16_t BTw[128 * 104];  // weighted B^T (n,t)
  __shared__ float ldas[8][96];
  __shared__ float dts[8][96];
  __shared__ float cums[8][96];
  __shared__ float wts[8][96];

  // ---- stage B, C (bf16 direct, 16B chunks) ----
  for (int i = tid; i < 96 * 32; i += 512) {
    int t = i >> 5, g = i & 31;
    bf16x8 v = *(const bf16x8*)(conv + (row0 + t) * CONVDIM + DINNER + g * 8);
    if (g < 16) *(bf16x8*)(Bb + t * 136 + g * 8) = v;
    else        *(bf16x8*)(Cb + t * 136 + (g - 16) * 8) = v;
  }
  // ---- stage dt, ldA for 8 heads ----
  for (int i = tid; i < 768; i += 512) {
    int hh = i & 7, t = i >> 3;
    size_t gi = (row0 + t) * NHEADS + h0 + hh;
    dts[hh][t]  = dtb[gi];
    ldas[hh][t] = ldAb[gi];
  }
  __syncthreads();
  // ---- cum prefix (serial per head, 8 threads) ----
  if (tid < 8) {
    float cacc = 0.f;
    for (int t = 0; t < 96; ++t) { cacc += ldas[tid][t]; cums[tid][t] = cacc; }
  }
  __syncthreads();
  // ---- state weights + chunkprod + cum export (for ycorr) ----
  for (int i = tid; i < 768; i += 512) {
    int hh = i & 7, t = i >> 3;
    wts[hh][t] = expf(cums[hh][95] - cums[hh][t]) * dts[hh][t];
    cumb[(row0 + t) * NHEADS + h0 + hh] = cums[hh][t];
  }
  if (tid < 8)
    chunkprod[(b * NHEADS + h0 + tid) * NCH + c] = expf(cums[tid][95]);

  // ---- G = C * B^T : 36 tiles of 16x16, wave w owns tiles {w, w+8, ...} ----
  floatx4 gacc[5];
  #pragma unroll
  for (int it = 0; it < 5; ++it) gacc[it] = (floatx4){0.f, 0.f, 0.f, 0.f};
  const int l16 = lane & 15, lk = (lane >> 4) << 3;
  #pragma unroll
  for (int it = 0; it < 5; ++it) {
    int tt = w + it * 8;
    int ti = (tt < 36) ? (tt / 6) : 0;
    int si = (tt < 36) ? (tt % 6) : 0;
    #pragma unroll
    for (int ks = 0; ks < 4; ++ks) {
      bf16x8 a = *(const bf16x8*)(Cb + (ti * 16 + l16) * 136 + ks * 32 + lk);
      bf16x8 bb = *(const bf16x8*)(Bb + (si * 16 + l16) * 136 + ks * 32 + lk);
      gacc[it] = __builtin_amdgcn_mfma_f32_16x16x32_bf16(a, bb, gacc[it], 0, 0, 0);
    }
  }

  // ---- per-head: build xT, BTw, P; then PX and S MFMA ----
  for (int hh = 0; hh < 8; ++hh) {
    __syncthreads();                    // prev head's MFMA readers done
    // x^T (p,t): 16B global loads, bit-move LDS transpose stores (no bf16 conversions)
    for (int i = tid; i < 768; i += 512) {
      int t = i >> 3, p8 = (i & 7) * 8;
      union { bf16x8 v8; unsigned short s[8]; } u;
      u.v8 = *(const bf16x8*)(conv + (row0 + t) * CONVDIM + (h0 + hh) * HEADDIM + p8);
      #pragma unroll
      for (int r = 0; r < 8; ++r)
        ((unsigned short*)xT)[(p8 + r) * 104 + t] = u.s[r];
    }
    // weighted B^T (n,t) bf16
    for (int i = tid; i < 128 * 96; i += 512) {
      int n = i / 96, t = i - n * 96;
      float bv = __bfloat162float(Bb[t * 136 + n]);
      BTw[n * 104 + t] = __float2bfloat16(wts[hh][t] * bv);
    }
    // P from G frags (wave-local registers)
    #pragma unroll
    for (int it = 0; it < 5; ++it) {
      int tt = w + it * 8;
      if (tt < 36) {
        int ti = tt / 6, si = tt % 6;
        int scol = si * 16 + l16;
        #pragma unroll
        for (int r = 0; r < 4; ++r) {
          int trow = ti * 16 + ((lane >> 4) << 2) + r;
          float pv = 0.f;
          if (scol <= trow)
            pv = expf(cums[hh][trow] - cums[hh][scol]) * dts[hh][scol] * gacc[it][r];
          Pl[trow * 104 + scol] = __float2bfloat16(pv);
        }
      }
    }
    __syncthreads();                    // builds visible
    float Dh = Dp[h0 + hh];
    // y = P @ x : 24 tiles (6 t x 4 p), 3 per wave
    #pragma unroll
    for (int it = 0; it < 3; ++it) {
      int tt = w + it * 8;
      int ti = tt >> 2, pi = tt & 3;
      floatx4 acc = (floatx4){0.f, 0.f, 0.f, 0.f};
      #pragma unroll
      for (int ks = 0; ks < 3; ++ks) {
        bf16x8 a = *(const bf16x8*)(Pl + (ti * 16 + l16) * 104 + ks * 32 + lk);
        bf16x8 bb = *(const bf16x8*)(xT + (pi * 16 + l16) * 104 + ks * 32 + lk);
        acc = __builtin_amdgcn_mfma_f32_16x16x32_bf16(a, bb, acc, 0, 0, 0);
      }
      int p = pi * 16 + l16;
      #pragma unroll
      for (int r = 0; r < 4; ++r) {
        int t = ti * 16 + ((lane >> 4) << 2) + r;
        float xg = __bfloat162float(conv[(row0 + t) * CONVDIM + (h0 + hh) * HEADDIM + p]);
        y[((row0 + t) * NHEADS + h0 + hh) * HEADDIM + p] = acc[r] + Dh * xg;
      }
    }
    // S = BTw @ x : 32 tiles (8 n x 4 p), 4 per wave
    size_t sb = ((size_t)(b * NHEADS + h0 + hh) * NCH + c) * STATESZ;
    #pragma unroll
    for (int it = 0; it < 4; ++it) {
      int tt = w + it * 8;
      int ni = tt >> 2, pi = tt & 3;
      floatx4 acc = (floatx4){0.f, 0.f, 0.f, 0.f};
      #pragma unroll
      for (int ks = 0; ks < 3; ++ks) {
        bf16x8 a = *(const bf16x8*)(BTw + (ni * 16 + l16) * 104 + ks * 32 + lk);
        bf16x8 bb = *(const bf16x8*)(xT + (pi * 16 + l16) * 104 + ks * 32 + lk);
        acc = __builtin_amdgcn_mfma_f32_16x16x32_bf16(a, bb, acc, 0, 0, 0);
      }
      int p = pi * 16 + l16;
      #pragma unroll
      for (int r = 0; r < 4; ++r) {
        int n = ni * 16 + ((lane >> 4) << 2) + r;
        state[sb + (size_t)n * HEADDIM + p] = acc[r];
      }
    }
  }
}

// ---------------- inter-chunk state recurrence: H_in[c] = P[c-1]*H_in[c-1] + S[c-1] ----------------
__global__ __launch_bounds__(256) void state_combine_kernel(float* __restrict__ state,
    const float* __restrict__ cprod) {
  int bh = blockIdx.y;
  int sl = blockIdx.x;            // slice 0..7 (1024 floats each)
  int tid = threadIdx.x;
  float4* slab = (float4*)(state + (size_t)bh * NCH * STATESZ) + sl * 256 + tid;
  const float* pc = cprod + bh * NCH;
  float4 H = make_float4(0.f, 0.f, 0.f, 0.f);
  for (int c = 1; c < NCH; ++c) {
    float P = pc[c - 1];
    float4* sp = slab + (size_t)(c - 1) * (STATESZ / 4);
    float4 S = *sp;
    H.x = P * H.x + S.x; H.y = P * H.y + S.y;
    H.z = P * H.z + S.z; H.w = P * H.w + S.w;
    *sp = H;
  }
}

// ---------------- pass 2 (MFMA): y[t] += cA[t] * (C_t . H_in)  per (chunk>=1, 8 heads) ----------------
// C staged once (shared across heads); per head H_in transposed to bf16 LDS; 24 MFMA
// tiles; per-head cA scale applied in f32 epilogue. cA from cumbuf (exported by scan).
__global__ __launch_bounds__(512) void ycorr_mfma_kernel(const bf16_t* __restrict__ conv,
    const float* __restrict__ cumb, const float* __restrict__ state,
    float* __restrict__ y) {
  const int c  = blockIdx.x + 1;             // chunk 1..7
  const int b  = blockIdx.y >> 1;
  const int h0 = (blockIdx.y & 1) * 8;
  const int tid  = threadIdx.x;              // 0..511
  const int w    = tid >> 6;
  const int lane = tid & 63;
  const int l16 = lane & 15, lk = (lane >> 4) << 3;
  const size_t row0 = (size_t)(b * SEQ + c * CH);

  __shared__ __align__(16) bf16_t Cb[96 * 136];   // C rows (t,n)
  __shared__ __align__(16) bf16_t HT[64 * 136];   // H^T (p,n) bf16
  __shared__ float cAs[8][96];

  // stage C rows (bf16 16B chunks): 96 rows x 16 groups
  for (int i = tid; i < 96 * 16; i += 512) {
    int t = i >> 4, g = i & 15;
    bf16x8 v = *(const bf16x8*)(conv + (row0 + t) * CONVDIM + DINNER + DSTATE + g * 8);
    *(bf16x8*)(Cb + t * 136 + g * 8) = v;
  }
  // stage cA = exp(cum) for 8 heads
  for (int i = tid; i < 768; i += 512) {
    int hh = i & 7, t = i >> 3;
    cAs[hh][t] = expf(cumb[(row0 + t) * NHEADS + h0 + hh]);
  }

  for (int hh = 0; hh < 8; ++hh) {
    __syncthreads();                    // prev head's MFMA readers done (and C/cA visible)
    // H^T build: read state coalesced (n-major), write transposed bf16
    const float* Hs = state + ((size_t)(b * NHEADS + h0 + hh) * NCH + (c - 1)) * STATESZ;
    for (int i = tid; i < STATESZ; i += 512) {
      int n = i >> 6, p = i & 63;
      HT[p * 136 + n] = __float2bfloat16(Hs[i]);
    }
    __syncthreads();
    // y += cA * (C @ H): 24 tiles (6 t x 4 p), 3 per wave, K=128 (4 k-steps)
    #pragma unroll
    for (int it = 0; it < 3; ++it) {
      int tt = w + it * 8;
      int ti = tt >> 2, pi = tt & 3;
      floatx4 acc = (floatx4){0.f, 0.f, 0.f, 0.f};
      #pragma unroll
      for (int ks = 0; ks < 4; ++ks) {
        bf16x8 a = *(const bf16x8*)(Cb + (ti * 16 + l16) * 136 + ks * 32 + lk);
        bf16x8 bb = *(const bf16x8*)(HT + (pi * 16 + l16) * 136 + ks * 32 + lk);
        acc = __builtin_amdgcn_mfma_f32_16x16x32_bf16(a, bb, acc, 0, 0, 0);
      }
      int p = pi * 16 + l16;
      #pragma unroll
      for (int r = 0; r < 4; ++r) {
        int t = ti * 16 + ((lane >> 4) << 2) + r;
        size_t yi = ((row0 + t) * NHEADS + h0 + hh) * HEADDIM + p;
        y[yi] += cAs[hh][t] * acc[r];
      }
    }
  }
}

// ---------------- gated RMSNorm over 1024, bf16 out ----------------
__global__ __launch_bounds__(256) void gated_norm_kernel(const float* __restrict__ y,
    const bf16_t* __restrict__ zx, const float* __restrict__ gw, bf16_t* __restrict__ out) {
  int row = blockIdx.x;
  int tid = threadIdx.x;
  const float4* y4 = (const float4*)(y + (size_t)row * DINNER);
  float4 yv = y4[tid];
  union { ushort4 u; bf16_t b[4]; } zq;
  zq.u = ((const ushort4*)(zx + (size_t)row * DINPROJ))[tid];
  float4 zv = make_float4(__bfloat162float(zq.b[0]), __bfloat162float(zq.b[1]),
                          __bfloat162float(zq.b[2]), __bfloat162float(zq.b[3]));
  float4 g;
  g.x = yv.x * siluf(zv.x); g.y = yv.y * siluf(zv.y);
  g.z = yv.z * siluf(zv.z); g.w = yv.w * siluf(zv.w);
  float ss = g.x * g.x + g.y * g.y + g.z * g.z + g.w * g.w;
  #pragma unroll
  for (int o = 32; o > 0; o >>= 1) ss += __shfl_down(ss, o);
  __shared__ float red[4];
  if ((tid & 63) == 0) red[tid >> 6] = ss;
  __syncthreads();
  float tot = red[0] + red[1] + red[2] + red[3];
  float scale = rsqrtf(tot / (float)DINNER + EPSV);
  const float4* g4 = (const float4*)gw;
  float4 wv = g4[tid];
  union { bf16_t b[4]; uint2 u; } pk;
  pk.b[0] = __float2bfloat16(g.x * scale * wv.x);
  pk.b[1] = __float2bfloat16(g.y * scale * wv.y);
  pk.b[2] = __float2bfloat16(g.z * scale * wv.z);
  pk.b[3] = __float2bfloat16(g.w * scale * wv.w);
  ((uint2*)(out + (size_t)row * DINNER))[tid] = pk.u;
}

// ---------------- per-row loss: lse - logit[target] ----------------
__global__ __launch_bounds__(256) void rowloss_kernel(const float* __restrict__ logits,
    const int* __restrict__ targets, float* __restrict__ rl) {
  int row = blockIdx.x * 4 + (threadIdx.x >> 6);
  int lane = threadIdx.x & 63;
  const float* lr = logits + (size_t)row * VOCABSZ;
  float4 v = ((const float4*)lr)[lane];
  float mx = fmaxf(fmaxf(v.x, v.y), fmaxf(v.z, v.w));
  #pragma unroll
  for (int o = 32; o > 0; o >>= 1) mx = fmaxf(mx, __shfl_down(mx, o));
  mx = __shfl(mx, 0);
  float e = expf(v.x - mx) + expf(v.y - mx) + expf(v.z - mx) + expf(v.w - mx);
  #pragma unroll
  for (int o = 32; o > 0; o >>= 1) e += __shfl_down(e, o);
  if (lane == 0) {
    float lse = logf(e) + mx;
    rl[row] = lse - lr[targets[row]];
  }
}

__global__ __launch_bounds__(256) void loss_reduce_kernel(const float* __restrict__ rl,
    float* __restrict__ out) {
  int tid = threadIdx.x;
  float ssum = 0.f;
  for (int i = tid; i < NROWS; i += 256) ssum += rl[i];
  #pragma unroll
  for (int o = 32; o > 0; o >>= 1) ssum += __shfl_down(ssum, o);
  __shared__ float red[4];
  if ((tid & 63) == 0) red[tid >> 6] = ssum;
  __syncthreads();
  if (tid == 0) out[0] = (red[0] + red[1] + red[2] + red[3]) / (float)NROWS;
}

extern "C" void kernel_launch(void* const* d_in, const int* in_sizes, int n_in,
                              void* d_out, int out_size, void* d_ws, size_t ws_size,
                              hipStream_t stream) {
  const int*   tokens       = (const int*)d_in[0];
  const int*   targets      = (const int*)d_in[1];
  const float* embedding    = (const float*)d_in[2];
  const float* in_proj_w    = (const float*)d_in[3];
  const float* conv_w       = (const float*)d_in[4];
  const float* conv_b       = (const float*)d_in[5];
  const float* dt_bias      = (const float*)d_in[6];
  const float* A_log        = (const float*)d_in[7];
  const float* Dp           = (const float*)d_in[8];
  const float* gnorm_w      = (const float*)d_in[9];
  const float* out_proj_w   = (const float*)d_in[10];
  const float* block_norm_w = (const float*)d_in[11];
  const float* norm_f_w     = (const float*)d_in[12];
  float* out = (float*)d_out;

  float* ws = (float*)d_ws;
  size_t off = 0;
  float* hidden   = ws + off; off += (size_t)NROWS * DMODEL;
  float* residual = ws + off; off += (size_t)NROWS * DMODEL;
  bf16_t* zx      = (bf16_t*)(ws + off); off += (size_t)NROWS * DINPROJ / 2;
  float* dtcol    = ws + off; off += (size_t)NROWS * NHEADS;
  bf16_t* convo   = (bf16_t*)(ws + off); off += (size_t)NROWS * CONVDIM / 2;
  float* dtb      = ws + off; off += (size_t)NROWS * NHEADS;
  float* ldAb     = ws + off; off += (size_t)NROWS * NHEADS;
  float* cumbuf   = ws + off; off += (size_t)NROWS * NHEADS;
  float* ybuf     = ws + off; off += (size_t)NROWS * DINNER;
  float* cprod    = ws + off; off += (size_t)BATCH * NHEADS * NCH;
  float* rowloss  = ws + off; off += NROWS;
  bf16_t* w_in_bf  = (bf16_t*)(ws + off); off += (size_t)DINPROJP * DMODEL / 2;
  bf16_t* w_out_bf = (bf16_t*)(ws + off); off += (size_t)DMODEL * DINNER / 2;
  bf16_t* w_emb_bf = (bf16_t*)(ws + off); off += (size_t)VOCABSZ * DMODEL / 2;
  // union region: state (16.78M floats) vs bf16 activations (disjoint live ranges)
  float*  state  = ws + off;
  bf16_t* xn_bf  = (bf16_t*)(ws + off);   // live prenorm -> gemm1
  bf16_t* yn_bf  = (bf16_t*)(ws + off);   // live gated_norm -> gemm2
  off += (size_t)BATCH * NHEADS * NCH * STATESZ;

  embed_kernel<<<(NROWS * DMODEL + VOCABSZ * DMODEL) / 256, 256, 0, stream>>>(
      tokens, embedding, hidden, residual, w_emb_bf);

  const int cvt_total = DINPROJP * DMODEL + DMODEL * DINNER;
  for (int l = 0; l < NLAYER; ++l) {
    const float* ipw = in_proj_w + (size_t)l * DINPROJ * DMODEL;
    const float* cw  = conv_w + (size_t)l * CONVDIM * 4;
    const float* cb  = conv_b + (size_t)l * CONVDIM;
    const float* dtbias_l = dt_bias + (size_t)l * NHEADS;
    const float* alog_l   = A_log + (size_t)l * NHEADS;
    const float* D_l      = Dp + (size_t)l * NHEADS;
    const float* gw  = gnorm_w + (size_t)l * DINNER;
    const float* opw = out_proj_w + (size_t)l * DMODEL * DINNER;
    const float* bnw = block_norm_w + (size_t)l * DMODEL;

    cvt_weights_kernel<<<(cvt_total + 255) / 256, 256, 0, stream>>>(ipw, opw, w_in_bf, w_out_bf);
    prenorm_kernel<<<NROWS, 128, 0, stream>>>(hidden, residual, bnw, xn_bf);
    dim3 g1(DINPROJP / 128, NROWS / 128);
    gemm_bf16_bt<128, bf16_t><<<g1, 256, 0, stream>>>(xn_bf, w_in_bf, zx, dtcol,
                                                      NROWS, DINPROJ, DMODEL);
    convdt_kernel<<<NROWS / 4, 320, 0, stream>>>(zx, dtcol, cw, cb, dtbias_l, alog_l,
                                                 convo, dtb, ldAb);
    scan_mfma_kernel<<<dim3(NCH, BATCH * 2), 512, 0, stream>>>(
        convo, dtb, ldAb, D_l, ybuf, state, cprod, cumbuf);
    state_combine_kernel<<<dim3(NCH, BATCH * NHEADS), 256, 0, stream>>>(state, cprod);
    ycorr_mfma_kernel<<<dim3(NCH - 1, BATCH * 2), 512, 0, stream>>>(
        convo, cumbuf, state, ybuf);
    gated_norm_kernel<<<NROWS, 256, 0, stream>>>(ybuf, zx, gw, yn_bf);
    dim3 g2(DMODEL / 64, NROWS / 128);
    gemm_bf16_bt<64, float><<<g2, 256, 0, stream>>>(yn_bf, w_out_bf, hidden, nullptr,
                                                    NROWS, DMODEL, DINNER);
  }

  prenorm_kernel<<<NROWS, 128, 0, stream>>>(hidden, residual, norm_f_w, xn_bf);
  dim3 g3(VOCABSZ / 64, NROWS / 128);
  gemm_bf16_bt<64, float><<<g3, 256, 0, stream>>>(xn_bf, w_emb_bf, out, nullptr,
                                                  NROWS, VOCABSZ, DMODEL);
  rowloss_kernel<<<NROWS / 4, 256, 0, stream>>>(out, targets, rowloss);
  loss_reduce_kernel<<<1, 256, 0, stream>>>(rowloss, out + (size_t)(out_size - 1));
}